// Round 1
// baseline (6804.516 us; speedup 1.0000x reference)
//
#include <hip/hip_runtime.h>
#include <math.h>

#define NB 8
#define C2 512
#define C3 1024
#define H2 28
#define W2 28
#define H3 14
#define W3 14
#define EDIM 1536
#define PPB (H2*W2)            /* 784 */
#define NPATCH (NB*PPB)        /* 6272 */
#define MBANK 20000
#define OUTW 224
#define NNB 9
#define KS 33
#define KR 16
#define NSPLIT 16
#define NTILE ((MBANK + 127)/128)  /* 157 */

// ---------------- feature pooling / embedding ----------------

__global__ void pool2_kernel(const float* __restrict__ in, float* __restrict__ emb) {
  int id = blockIdx.x*blockDim.x + threadIdx.x;
  if (id >= NB*C2*H2*W2) return;
  int w = id % W2, h = (id / W2) % H2, c = (id / (H2*W2)) % C2, b = id / (C2*H2*W2);
  const float* src = in + (size_t)(b*C2 + c)*H2*W2;
  float s = 0.f;
  #pragma unroll
  for (int dh=-1; dh<=1; ++dh) {
    int hh = h+dh; if (hh<0||hh>=H2) continue;
    #pragma unroll
    for (int dw=-1; dw<=1; ++dw) {
      int ww = w+dw; if (ww<0||ww>=W2) continue;
      s += src[hh*W2+ww];
    }
  }
  emb[((size_t)(b*PPB) + h*W2 + w)*EDIM + c] = s * (1.f/9.f);
}

__global__ void pool3_kernel(const float* __restrict__ in, float* __restrict__ f3p) {
  int id = blockIdx.x*blockDim.x + threadIdx.x;
  if (id >= NB*C3*H3*W3) return;
  int w = id % W3, h = (id / W3) % H3, c = (id / (H3*W3)) % C3, b = id / (C3*H3*W3);
  const float* src = in + (size_t)(b*C3 + c)*H3*W3;
  float s = 0.f;
  #pragma unroll
  for (int dh=-1; dh<=1; ++dh) {
    int hh = h+dh; if (hh<0||hh>=H3) continue;
    #pragma unroll
    for (int dw=-1; dw<=1; ++dw) {
      int ww = w+dw; if (ww<0||ww>=W3) continue;
      s += src[hh*W3+ww];
    }
  }
  f3p[(size_t)id] = s * (1.f/9.f);
}

__global__ void up3_kernel(const float* __restrict__ f3p, float* __restrict__ emb) {
  int id = blockIdx.x*blockDim.x + threadIdx.x;
  if (id >= NB*C3*H2*W2) return;
  int j = id % W2, i = (id/W2)%H2, c = (id/(H2*W2))%C3, b = id/(C3*H2*W2);
  float sy = i*0.5f - 0.25f; sy = fminf(fmaxf(sy,0.f),(float)(H3-1));
  int y0 = (int)sy; int y1 = min(y0+1,H3-1); float fy = sy - (float)y0;
  float sx = j*0.5f - 0.25f; sx = fminf(fmaxf(sx,0.f),(float)(W3-1));
  int x0 = (int)sx; int x1 = min(x0+1,W3-1); float fx = sx - (float)x0;
  const float* p = f3p + (size_t)(b*C3+c)*H3*W3;
  float v = (1.f-fy)*((1.f-fx)*p[y0*W3+x0] + fx*p[y0*W3+x1])
          +      fy *((1.f-fx)*p[y1*W3+x0] + fx*p[y1*W3+x1]);
  emb[((size_t)(b*PPB) + i*W2 + j)*EDIM + C2 + c] = v;
}

// ---------------- row norms ----------------

__global__ void norm_kernel(const float* __restrict__ src, float* __restrict__ norms, int rows) {
  int w = (blockIdx.x*blockDim.x + threadIdx.x) >> 6;
  int lane = threadIdx.x & 63;
  if (w >= rows) return;
  const float* p = src + (size_t)w*EDIM;
  float acc = 0.f;
  for (int k = lane; k < EDIM; k += 64) { float v = p[k]; acc = fmaf(v, v, acc); }
  #pragma unroll
  for (int s = 32; s; s >>= 1) acc += __shfl_xor(acc, s);
  if (lane == 0) norms[w] = acc;
}

// ---------------- fused distance GEMM + min/argmin ----------------

__global__ __launch_bounds__(256) void dist_min_kernel(
    const float* __restrict__ A, const float* __restrict__ B,
    const float* __restrict__ xn, const float* __restrict__ yn,
    float* __restrict__ outv, int* __restrict__ outi)
{
  __shared__ float As[16][132];
  __shared__ float Bs[16][132];
  const int t = threadIdx.x;
  const int tx = t & 15, ty = t >> 4;
  const int n0 = blockIdx.y * 128;
  const int split = blockIdx.x;
  const int mt_begin = (split * NTILE) / NSPLIT;
  const int mt_end   = ((split + 1) * NTILE) / NSPLIT;

  float bestv[8]; int besti[8];
  #pragma unroll
  for (int i = 0; i < 8; ++i) { bestv[i] = INFINITY; besti[i] = 0x7fffffff; }

  float xr[8];
  #pragma unroll
  for (int i = 0; i < 8; ++i) {
    int row = ty*4 + (i&3) + (i>>2)*64;
    xr[i] = xn[n0 + row];
  }

  for (int mt = mt_begin; mt < mt_end; ++mt) {
    const int m0 = mt * 128;
    float acc[8][8];
    #pragma unroll
    for (int i=0;i<8;++i)
      #pragma unroll
      for (int j=0;j<8;++j) acc[i][j] = 0.f;

    for (int k0 = 0; k0 < EDIM; k0 += 16) {
      __syncthreads();
      #pragma unroll
      for (int rep = 0; rep < 2; ++rep) {
        int c  = t + rep*256;
        int r  = c >> 2;
        int kq = (c & 3) * 4;
        const float4 va = *reinterpret_cast<const float4*>(&A[(size_t)(n0 + r)*EDIM + k0 + kq]);
        As[kq+0][r] = va.x; As[kq+1][r] = va.y; As[kq+2][r] = va.z; As[kq+3][r] = va.w;
        int br = m0 + r; if (br > MBANK-1) br = MBANK-1;
        const float4 vb = *reinterpret_cast<const float4*>(&B[(size_t)br*EDIM + k0 + kq]);
        Bs[kq+0][r] = vb.x; Bs[kq+1][r] = vb.y; Bs[kq+2][r] = vb.z; Bs[kq+3][r] = vb.w;
      }
      __syncthreads();
      #pragma unroll
      for (int k = 0; k < 16; ++k) {
        const float4 a0 = *reinterpret_cast<const float4*>(&As[k][ty*4]);
        const float4 a1 = *reinterpret_cast<const float4*>(&As[k][64 + ty*4]);
        const float4 b0 = *reinterpret_cast<const float4*>(&Bs[k][tx*4]);
        const float4 b1 = *reinterpret_cast<const float4*>(&Bs[k][64 + tx*4]);
        const float av[8] = {a0.x,a0.y,a0.z,a0.w,a1.x,a1.y,a1.z,a1.w};
        const float bv[8] = {b0.x,b0.y,b0.z,b0.w,b1.x,b1.y,b1.z,b1.w};
        #pragma unroll
        for (int i=0;i<8;++i)
          #pragma unroll
          for (int j=0;j<8;++j) acc[i][j] = fmaf(av[i], bv[j], acc[i][j]);
      }
    }

    #pragma unroll
    for (int j = 0; j < 8; ++j) {
      int col = m0 + tx*4 + (j&3) + (j>>2)*64;
      if (col < MBANK) {
        float ynv = yn[col];
        #pragma unroll
        for (int i = 0; i < 8; ++i) {
          float d2 = xr[i] - 2.f*acc[i][j] + ynv;
          float d = sqrtf(fmaxf(d2, 0.f));
          if (d < bestv[i] || (d == bestv[i] && col < besti[i])) { bestv[i] = d; besti[i] = col; }
        }
      }
    }
  }

  #pragma unroll
  for (int i = 0; i < 8; ++i) {
    float v = bestv[i]; int ix = besti[i];
    #pragma unroll
    for (int m = 1; m < 16; m <<= 1) {
      float ov = __shfl_xor(v, m);
      int   oi = __shfl_xor(ix, m);
      if (ov < v || (ov == v && oi < ix)) { v = ov; ix = oi; }
    }
    if (tx == 0) {
      int row = n0 + ty*4 + (i&3) + (i>>2)*64;
      outv[(size_t)row * NSPLIT + split] = v;
      outi[(size_t)row * NSPLIT + split] = ix;
    }
  }
}

__global__ void reduce_min_kernel(const float* __restrict__ outv, const int* __restrict__ outi,
                                  float* __restrict__ ps, int* __restrict__ loc) {
  int r = blockIdx.x*blockDim.x + threadIdx.x;
  if (r >= NPATCH) return;
  float bv = INFINITY; int bi = 0x7fffffff;
  for (int s = 0; s < NSPLIT; ++s) {
    float v = outv[(size_t)r*NSPLIT + s];
    int  ix = outi[(size_t)r*NSPLIT + s];
    if (v < bv || (v == bv && ix < bi)) { bv = v; bi = ix; }
  }
  ps[r] = bv; loc[r] = bi;
}

// ---------------- anomaly score ----------------

__global__ void argmax_kernel(const float* __restrict__ ps, const int* __restrict__ loc,
                              float* __restrict__ bscore, int* __restrict__ brow, int* __restrict__ bnn) {
  __shared__ float sv[256]; __shared__ int si[256];
  int b = blockIdx.x, t = threadIdx.x;
  float bv = -INFINITY; int bi = 0x7fffffff;
  for (int p = t; p < PPB; p += 256) {
    float v = ps[b*PPB + p];
    if (v > bv || (v == bv && p < bi)) { bv = v; bi = p; }
  }
  sv[t] = bv; si[t] = bi; __syncthreads();
  for (int s = 128; s; s >>= 1) {
    if (t < s) {
      if (sv[t+s] > sv[t] || (sv[t+s] == sv[t] && si[t+s] < si[t])) { sv[t] = sv[t+s]; si[t] = si[t+s]; }
    }
    __syncthreads();
  }
  if (t == 0) {
    bscore[b] = sv[0];
    brow[b]   = b*PPB + si[0];
    bnn[b]    = loc[b*PPB + si[0]];
  }
}

__global__ void dbank_kernel(const float* __restrict__ bank, const float* __restrict__ yn,
                             const int* __restrict__ bnn, float* __restrict__ dbank) {
  int w = (blockIdx.x*blockDim.x + threadIdx.x) >> 6;
  int lane = threadIdx.x & 63;
  if (w >= NB*MBANK) return;
  int b = w / MBANK, m = w % MBANK;
  int nn = bnn[b];
  const float* x = bank + (size_t)nn*EDIM;
  const float* y = bank + (size_t)m*EDIM;
  float acc = 0.f;
  for (int k = lane; k < EDIM; k += 64) acc = fmaf(x[k], y[k], acc);
  #pragma unroll
  for (int s = 32; s; s >>= 1) acc += __shfl_xor(acc, s);
  if (lane == 0) {
    float d2 = yn[nn] - 2.f*acc + yn[m];
    dbank[(size_t)b*MBANK + m] = sqrtf(fmaxf(d2, 0.f));
  }
}

__global__ void top9_kernel(float* __restrict__ dbank, int* __restrict__ support) {
  __shared__ float sv[256]; __shared__ int si[256];
  int b = blockIdx.x, t = threadIdx.x;
  float* db = dbank + (size_t)b*MBANK;
  for (int r = 0; r < NNB; ++r) {
    float bv = INFINITY; int bi = 0x7fffffff;
    for (int m = t; m < MBANK; m += 256) {
      float v = db[m];
      if (v < bv || (v == bv && m < bi)) { bv = v; bi = m; }
    }
    sv[t] = bv; si[t] = bi; __syncthreads();
    for (int s = 128; s; s >>= 1) {
      if (t < s) {
        if (sv[t+s] < sv[t] || (sv[t+s] == sv[t] && si[t+s] < si[t])) { sv[t] = sv[t+s]; si[t] = si[t+s]; }
      }
      __syncthreads();
    }
    if (t == 0) { support[b*NNB + r] = si[0]; db[si[0]] = INFINITY; }
    __syncthreads();
  }
}

__global__ void dsup_kernel(const float* __restrict__ emb, const float* __restrict__ bank,
                            const float* __restrict__ xn, const float* __restrict__ yn,
                            const int* __restrict__ brow, const int* __restrict__ support,
                            float* __restrict__ dsup) {
  int w = (blockIdx.x*blockDim.x + threadIdx.x) >> 6;
  int lane = threadIdx.x & 63;
  if (w >= NB*NNB) return;
  int b = w / NNB, j = w % NNB;
  int row = brow[b]; int sup = support[b*NNB + j];
  const float* x = emb  + (size_t)row*EDIM;
  const float* y = bank + (size_t)sup*EDIM;
  float acc = 0.f;
  for (int k = lane; k < EDIM; k += 64) acc = fmaf(x[k], y[k], acc);
  #pragma unroll
  for (int s = 32; s; s >>= 1) acc += __shfl_xor(acc, s);
  if (lane == 0) dsup[b*NNB + j] = sqrtf(fmaxf(xn[row] - 2.f*acc + yn[sup], 0.f));
}

__global__ void pred_kernel(const float* __restrict__ dsup, const float* __restrict__ bscore,
                            float* __restrict__ out) {
  int b = threadIdx.x;
  if (b >= NB) return;
  float d[NNB]; float mx = -INFINITY;
  #pragma unroll
  for (int j = 0; j < NNB; ++j) { d[j] = dsup[b*NNB + j]; mx = fmaxf(mx, d[j]); }
  float s = 0.f;
  #pragma unroll
  for (int j = 0; j < NNB; ++j) s += expf(d[j] - mx);
  float w = 1.f - expf(d[0] - mx) / s;
  out[b] = w * bscore[b];
}

// ---------------- anomaly map ----------------

__global__ void gk_kernel(float* __restrict__ gk) {
  if (threadIdx.x == 0 && blockIdx.x == 0) {
    float w[KS]; float s = 0.f;
    for (int t = 0; t < KS; ++t) {
      float x = (float)t - (float)KR;
      w[t] = expf(-(x*x) / (2.f*4.f*4.f));
      s += w[t];
    }
    for (int t = 0; t < KS; ++t) gk[t] = w[t] / s;
  }
}

__global__ void upmap_kernel(const float* __restrict__ ps, float* __restrict__ amap) {
  int id = blockIdx.x*blockDim.x + threadIdx.x;
  if (id >= NB*OUTW*OUTW) return;
  int j = id % OUTW, i = (id/OUTW) % OUTW, b = id/(OUTW*OUTW);
  float sy = ((float)i + 0.5f)*0.125f - 0.5f; sy = fminf(fmaxf(sy,0.f),(float)(H2-1));
  int y0 = (int)sy; int y1 = min(y0+1,H2-1); float fy = sy - (float)y0;
  float sx = ((float)j + 0.5f)*0.125f - 0.5f; sx = fminf(fmaxf(sx,0.f),(float)(W2-1));
  int x0 = (int)sx; int x1 = min(x0+1,W2-1); float fx = sx - (float)x0;
  const float* p = ps + b*PPB;
  amap[id] = (1.f-fy)*((1.f-fx)*p[y0*W2+x0] + fx*p[y0*W2+x1])
           +      fy *((1.f-fx)*p[y1*W2+x0] + fx*p[y1*W2+x1]);
}

__device__ __forceinline__ int refl224(int x) {
  if (x < 0) return -x;
  if (x > OUTW-1) return 2*(OUTW-1) - x;
  return x;
}

__global__ void blurh_kernel(const float* __restrict__ in, const float* __restrict__ gk,
                             float* __restrict__ out) {
  int id = blockIdx.x*blockDim.x + threadIdx.x;
  if (id >= NB*OUTW*OUTW) return;
  int j = id % OUTW;
  int base = id - j;
  float s = 0.f;
  #pragma unroll
  for (int v = 0; v < KS; ++v) {
    int jj = refl224(j - KR + v);
    s = fmaf(gk[v], in[base + jj], s);
  }
  out[id] = s;
}

__global__ void blurv_kernel(const float* __restrict__ in, const float* __restrict__ gk,
                             float* __restrict__ out) {
  int id = blockIdx.x*blockDim.x + threadIdx.x;
  if (id >= NB*OUTW*OUTW) return;
  int j = id % OUTW, i = (id/OUTW) % OUTW, b = id/(OUTW*OUTW);
  float s = 0.f;
  #pragma unroll
  for (int u = 0; u < KS; ++u) {
    int ii = refl224(i - KR + u);
    s = fmaf(gk[u], in[((size_t)b*OUTW + ii)*OUTW + j], s);
  }
  out[id] = s;
}

// ---------------- launch ----------------

extern "C" void kernel_launch(void* const* d_in, const int* in_sizes, int n_in,
                              void* d_out, int out_size, void* d_ws, size_t ws_size,
                              hipStream_t stream) {
  const float* feat2 = (const float*)d_in[0];
  const float* feat3 = (const float*)d_in[1];
  const float* bank  = (const float*)d_in[2];
  float* out = (float*)d_out;

  // bump allocator on workspace (float-sized slots, 256B aligned)
  char* base = (char*)d_ws;
  size_t off = 0;
  auto alloc = [&](size_t nfloats) -> char* {
    char* p = base + off;
    off += ((nfloats*4 + 255) & ~(size_t)255);
    return p;
  };
  float* emb    = (float*)alloc((size_t)NPATCH*EDIM);
  float* f3p    = (float*)alloc((size_t)NB*C3*H3*W3);
  float* yn     = (float*)alloc(MBANK);
  float* xn     = (float*)alloc(NPATCH);
  float* wsminv = (float*)alloc((size_t)NPATCH*NSPLIT);
  int*   wsargi = (int*)  alloc((size_t)NPATCH*NSPLIT);
  float* ps     = (float*)alloc(NPATCH);
  int*   loc    = (int*)  alloc(NPATCH);
  float* bscore = (float*)alloc(NB);
  int*   brow   = (int*)  alloc(NB);
  int*   bnn    = (int*)  alloc(NB);
  float* dbank  = (float*)alloc((size_t)NB*MBANK);
  int*   supp   = (int*)  alloc(NB*NNB);
  float* dsup   = (float*)alloc(NB*NNB);
  float* gk     = (float*)alloc(KS);
  float* amap   = (float*)alloc((size_t)NB*OUTW*OUTW);
  float* tmp    = (float*)alloc((size_t)NB*OUTW*OUTW);

  gk_kernel<<<1, 64, 0, stream>>>(gk);

  {
    int n = NB*C2*H2*W2;
    pool2_kernel<<<(n+255)/256, 256, 0, stream>>>(feat2, emb);
  }
  {
    int n = NB*C3*H3*W3;
    pool3_kernel<<<(n+255)/256, 256, 0, stream>>>(feat3, f3p);
  }
  {
    int n = NB*C3*H2*W2;
    up3_kernel<<<(n+255)/256, 256, 0, stream>>>(f3p, emb);
  }
  norm_kernel<<<(MBANK*64+255)/256, 256, 0, stream>>>(bank, yn, MBANK);
  norm_kernel<<<(NPATCH*64+255)/256, 256, 0, stream>>>(emb, xn, NPATCH);

  {
    dim3 grid(NSPLIT, NPATCH/128);
    dist_min_kernel<<<grid, 256, 0, stream>>>(emb, bank, xn, yn, wsminv, wsargi);
  }
  reduce_min_kernel<<<(NPATCH+255)/256, 256, 0, stream>>>(wsminv, wsargi, ps, loc);

  argmax_kernel<<<NB, 256, 0, stream>>>(ps, loc, bscore, brow, bnn);
  dbank_kernel<<<(NB*MBANK*64)/256, 256, 0, stream>>>(bank, yn, bnn, dbank);
  top9_kernel<<<NB, 256, 0, stream>>>(dbank, supp);
  dsup_kernel<<<(NB*NNB*64 + 255)/256, 256, 0, stream>>>(emb, bank, xn, yn, brow, supp, dsup);
  pred_kernel<<<1, 64, 0, stream>>>(dsup, bscore, out + NB*OUTW*OUTW);

  {
    int n = NB*OUTW*OUTW;
    upmap_kernel<<<(n+255)/256, 256, 0, stream>>>(ps, amap);
    blurh_kernel<<<(n+255)/256, 256, 0, stream>>>(amap, gk, tmp);
    blurv_kernel<<<(n+255)/256, 256, 0, stream>>>(tmp, gk, out);
  }
}

// Round 2
// 925.786 us; speedup vs baseline: 7.3500x; 7.3500x over previous
//
#include <hip/hip_runtime.h>
#include <math.h>

#define NB 8
#define C2 512
#define C3 1024
#define H2 28
#define W2 28
#define H3 14
#define W3 14
#define EDIM 1536
#define PPB (H2*W2)            /* 784 */
#define NPATCH (NB*PPB)        /* 6272 */
#define MBANK 20000
#define OUTW 224
#define NNB 9
#define KS 33
#define KR 16
#define NSPLIT 16
#define NTILE ((MBANK + 127)/128)  /* 157 */
#define BK 64
#define KTILES (EDIM/BK)           /* 24 */

typedef __attribute__((ext_vector_type(8))) short short8;
typedef __attribute__((ext_vector_type(4))) float f32x4;

__device__ __forceinline__ float bf2f(unsigned short u) {
  union { unsigned u; float f; } c; c.u = ((unsigned)u) << 16; return c.f;
}
__device__ __forceinline__ unsigned short f2bf(float f) {
  union { float f; unsigned u; } c; c.f = f;
  unsigned r = c.u + 0x7fff + ((c.u >> 16) & 1);
  return (unsigned short)(r >> 16);
}
__device__ __forceinline__ void gload16(const void* g, void* l) {
  __builtin_amdgcn_global_load_lds(
      (const __attribute__((address_space(1))) unsigned int*)g,
      (__attribute__((address_space(3))) unsigned int*)l, 16, 0, 0);
}

// ---------------- feature pooling / embedding (emb stored bf16) ----------------

__global__ void pool2_kernel(const float* __restrict__ in, unsigned short* __restrict__ emb) {
  int id = blockIdx.x*blockDim.x + threadIdx.x;
  if (id >= NB*C2*H2*W2) return;
  int w = id % W2, h = (id / W2) % H2, c = (id / (H2*W2)) % C2, b = id / (C2*H2*W2);
  const float* src = in + (size_t)(b*C2 + c)*H2*W2;
  float s = 0.f;
  #pragma unroll
  for (int dh=-1; dh<=1; ++dh) {
    int hh = h+dh; if (hh<0||hh>=H2) continue;
    #pragma unroll
    for (int dw=-1; dw<=1; ++dw) {
      int ww = w+dw; if (ww<0||ww>=W2) continue;
      s += src[hh*W2+ww];
    }
  }
  emb[((size_t)(b*PPB) + h*W2 + w)*EDIM + c] = f2bf(s * (1.f/9.f));
}

__global__ void pool3_kernel(const float* __restrict__ in, float* __restrict__ f3p) {
  int id = blockIdx.x*blockDim.x + threadIdx.x;
  if (id >= NB*C3*H3*W3) return;
  int w = id % W3, h = (id / W3) % H3, c = (id / (H3*W3)) % C3, b = id / (C3*H3*W3);
  const float* src = in + (size_t)(b*C3 + c)*H3*W3;
  float s = 0.f;
  #pragma unroll
  for (int dh=-1; dh<=1; ++dh) {
    int hh = h+dh; if (hh<0||hh>=H3) continue;
    #pragma unroll
    for (int dw=-1; dw<=1; ++dw) {
      int ww = w+dw; if (ww<0||ww>=W3) continue;
      s += src[hh*W3+ww];
    }
  }
  f3p[(size_t)id] = s * (1.f/9.f);
}

__global__ void up3_kernel(const float* __restrict__ f3p, unsigned short* __restrict__ emb) {
  int id = blockIdx.x*blockDim.x + threadIdx.x;
  if (id >= NB*C3*H2*W2) return;
  int j = id % W2, i = (id/W2)%H2, c = (id/(H2*W2))%C3, b = id/(C3*H2*W2);
  float sy = i*0.5f - 0.25f; sy = fminf(fmaxf(sy,0.f),(float)(H3-1));
  int y0 = (int)sy; int y1 = min(y0+1,H3-1); float fy = sy - (float)y0;
  float sx = j*0.5f - 0.25f; sx = fminf(fmaxf(sx,0.f),(float)(W3-1));
  int x0 = (int)sx; int x1 = min(x0+1,W3-1); float fx = sx - (float)x0;
  const float* p = f3p + (size_t)(b*C3+c)*H3*W3;
  float v = (1.f-fy)*((1.f-fx)*p[y0*W3+x0] + fx*p[y0*W3+x1])
          +      fy *((1.f-fx)*p[y1*W3+x0] + fx*p[y1*W3+x1]);
  emb[((size_t)(b*PPB) + i*W2 + j)*EDIM + C2 + c] = f2bf(v);
}

// ---------------- bank -> bf16 ----------------

__global__ void tobf16_kernel(const float* __restrict__ in, unsigned short* __restrict__ out, int n4) {
  int id = blockIdx.x*blockDim.x + threadIdx.x;
  if (id >= n4) return;
  float4 v = reinterpret_cast<const float4*>(in)[id];
  ushort4 o;
  o.x = f2bf(v.x); o.y = f2bf(v.y); o.z = f2bf(v.z); o.w = f2bf(v.w);
  reinterpret_cast<ushort4*>(out)[id] = o;
}

// ---------------- row norms ----------------

__global__ void norm_kernel(const float* __restrict__ src, float* __restrict__ norms, int rows) {
  int w = (blockIdx.x*blockDim.x + threadIdx.x) >> 6;
  int lane = threadIdx.x & 63;
  if (w >= rows) return;
  const float4* p = reinterpret_cast<const float4*>(src + (size_t)w*EDIM);
  float acc = 0.f;
  for (int k = lane; k < EDIM/4; k += 64) {
    float4 v = p[k];
    acc = fmaf(v.x,v.x,acc); acc = fmaf(v.y,v.y,acc);
    acc = fmaf(v.z,v.z,acc); acc = fmaf(v.w,v.w,acc);
  }
  #pragma unroll
  for (int s = 32; s; s >>= 1) acc += __shfl_xor(acc, s);
  if (lane == 0) norms[w] = acc;
}

__global__ void norm_bf16_kernel(const unsigned short* __restrict__ src, float* __restrict__ norms, int rows) {
  int w = (blockIdx.x*blockDim.x + threadIdx.x) >> 6;
  int lane = threadIdx.x & 63;
  if (w >= rows) return;
  const ushort4* p = reinterpret_cast<const ushort4*>(src + (size_t)w*EDIM);
  float acc = 0.f;
  for (int k = lane; k < EDIM/4; k += 64) {
    ushort4 v = p[k];
    float a = bf2f(v.x), b = bf2f(v.y), c = bf2f(v.z), d = bf2f(v.w);
    acc = fmaf(a,a,acc); acc = fmaf(b,b,acc); acc = fmaf(c,c,acc); acc = fmaf(d,d,acc);
  }
  #pragma unroll
  for (int s = 32; s; s >>= 1) acc += __shfl_xor(acc, s);
  if (lane == 0) norms[w] = acc;
}

// ---------------- fused bf16-MFMA distance GEMM + min/argmin ----------------
// A [NPATCH][EDIM] bf16, B [MBANK][EDIM] bf16 (B^T-gemm). 128x128 tile, BK=64.
// LDS rows are 128B; staging uses linear global_load_lds dest with the global
// source pre-swizzled by chunk^=(row&7); ds_read applies the same XOR.

__global__ __launch_bounds__(256, 2) void dist_min_mfma(
    const unsigned short* __restrict__ A, const unsigned short* __restrict__ B,
    const float* __restrict__ xn, const float* __restrict__ yn,
    float* __restrict__ outv, int* __restrict__ outi)
{
  __shared__ __align__(16) unsigned char AsB[16384];
  __shared__ __align__(16) unsigned char BsB[16384];
  const int t = threadIdx.x;
  const int lane = t & 63, wid = t >> 6;
  const int wr = wid >> 1, wc = wid & 1;
  const int n0 = blockIdx.y * 128;
  const int split = blockIdx.x;
  const int mt_begin = (split * NTILE) / NSPLIT;
  const int mt_end   = ((split + 1) * NTILE) / NSPLIT;

  // staging geometry: chunk c = wid*4+q; dest byte = c*1024 + lane*16
  // -> LDS row r = c*8 + (lane>>3), in-row chunk cpos = lane&7
  // -> global k-chunk gch = cpos ^ (r&7) = (lane&7) ^ (lane>>3)
  const int gch = (lane & 7) ^ (lane >> 3);
  const char* aSrc[4];
  #pragma unroll
  for (int q = 0; q < 4; ++q) {
    int ar = n0 + wid*32 + q*8 + (lane >> 3);
    aSrc[q] = (const char*)A + ((size_t)ar*EDIM + gch*8)*2;
  }
  char* aDst = (char*)AsB + wid*4096;
  char* bDst = (char*)BsB + wid*4096;

  // fragment read geometry
  const int abase = (wr*64 + (lane & 15)) * 128;
  const int bbase = (wc*64 + (lane & 15)) * 128;
  const int koff0 = (((lane >> 4)    ) ^ (lane & 7)) * 16;
  const int koff1 = (((lane >> 4) + 4) ^ (lane & 7)) * 16;

  float bq[4][4]; int bi[4][4];
  #pragma unroll
  for (int fi = 0; fi < 4; ++fi)
    #pragma unroll
    for (int r = 0; r < 4; ++r) { bq[fi][r] = INFINITY; bi[fi][r] = 0x7fffffff; }

  for (int mt = mt_begin; mt < mt_end; ++mt) {
    const int m0 = mt * 128;
    const char* bSrc[4];
    #pragma unroll
    for (int q = 0; q < 4; ++q) {
      int br = m0 + wid*32 + q*8 + (lane >> 3);
      if (br > MBANK-1) br = MBANK-1;
      bSrc[q] = (const char*)B + ((size_t)br*EDIM + gch*8)*2;
    }

    f32x4 acc[4][4];
    #pragma unroll
    for (int fi = 0; fi < 4; ++fi)
      #pragma unroll
      for (int fj = 0; fj < 4; ++fj) acc[fi][fj] = (f32x4){0.f,0.f,0.f,0.f};

    for (int kt = 0; kt < KTILES; ++kt) {
      const int kb = kt * 128;  // 64 bf16 = 128 bytes along K
      __syncthreads();
      #pragma unroll
      for (int q = 0; q < 4; ++q) gload16(aSrc[q] + kb, aDst + q*1024);
      #pragma unroll
      for (int q = 0; q < 4; ++q) gload16(bSrc[q] + kb, bDst + q*1024);
      __syncthreads();
      #pragma unroll
      for (int ks = 0; ks < 2; ++ks) {
        const int ko = ks ? koff1 : koff0;
        short8 af[4], bfr[4];
        #pragma unroll
        for (int fi = 0; fi < 4; ++fi)
          af[fi] = *reinterpret_cast<const short8*>(AsB + abase + fi*2048 + ko);
        #pragma unroll
        for (int fj = 0; fj < 4; ++fj)
          bfr[fj] = *reinterpret_cast<const short8*>(BsB + bbase + fj*2048 + ko);
        #pragma unroll
        for (int fi = 0; fi < 4; ++fi)
          #pragma unroll
          for (int fj = 0; fj < 4; ++fj)
            acc[fi][fj] = __builtin_amdgcn_mfma_f32_16x16x32_bf16(af[fi], bfr[fj], acc[fi][fj], 0, 0, 0);
      }
    }

    // epilogue: q = yn - 2*dot ; track min+argmin (xn/sqrt applied at write)
    #pragma unroll
    for (int fj = 0; fj < 4; ++fj) {
      int col = m0 + wc*64 + fj*16 + (lane & 15);
      float ynv = (col < MBANK) ? yn[col] : INFINITY;
      #pragma unroll
      for (int fi = 0; fi < 4; ++fi)
        #pragma unroll
        for (int r = 0; r < 4; ++r) {
          float q = fmaf(-2.f, acc[fi][fj][r], ynv);
          if (q < bq[fi][r] || (q == bq[fi][r] && col < bi[fi][r])) {
            bq[fi][r] = q; bi[fi][r] = col;
          }
        }
    }
  }

  // reduce across the 16 lanes of each row group, then across wc via LDS
  __syncthreads();
  float* sv = (float*)AsB;  // [128][2]
  int*   si = (int*)BsB;    // [128][2]
  #pragma unroll
  for (int fi = 0; fi < 4; ++fi)
    #pragma unroll
    for (int r = 0; r < 4; ++r) {
      float v = bq[fi][r]; int ix = bi[fi][r];
      #pragma unroll
      for (int m = 1; m < 16; m <<= 1) {
        float ov = __shfl_xor(v, m);
        int   oi = __shfl_xor(ix, m);
        if (ov < v || (ov == v && oi < ix)) { v = ov; ix = oi; }
      }
      if ((lane & 15) == 0) {
        int rl = wr*64 + fi*16 + (lane >> 4)*4 + r;
        sv[rl*2 + wc] = v; si[rl*2 + wc] = ix;
      }
    }
  __syncthreads();
  if (t < 128) {
    float q0 = sv[t*2], q1 = sv[t*2+1];
    int   i0 = si[t*2], i1 = si[t*2+1];
    float q; int ix;
    if (q1 < q0 || (q1 == q0 && i1 < i0)) { q = q1; ix = i1; } else { q = q0; ix = i0; }
    int row = n0 + t;
    float d = sqrtf(fmaxf(xn[row] + q, 0.f));
    outv[(size_t)row * NSPLIT + split] = d;
    outi[(size_t)row * NSPLIT + split] = ix;
  }
}

__global__ void reduce_min_kernel(const float* __restrict__ outv, const int* __restrict__ outi,
                                  float* __restrict__ ps, int* __restrict__ loc) {
  int r = blockIdx.x*blockDim.x + threadIdx.x;
  if (r >= NPATCH) return;
  float bv = INFINITY; int bi = 0x7fffffff;
  for (int s = 0; s < NSPLIT; ++s) {
    float v = outv[(size_t)r*NSPLIT + s];
    int  ix = outi[(size_t)r*NSPLIT + s];
    if (v < bv || (v == bv && ix < bi)) { bv = v; bi = ix; }
  }
  ps[r] = bv; loc[r] = bi;
}

// ---------------- anomaly score ----------------

__global__ void argmax_kernel(const float* __restrict__ ps, const int* __restrict__ loc,
                              float* __restrict__ bscore, int* __restrict__ brow, int* __restrict__ bnn) {
  __shared__ float sv[256]; __shared__ int si[256];
  int b = blockIdx.x, t = threadIdx.x;
  float bv = -INFINITY; int bi = 0x7fffffff;
  for (int p = t; p < PPB; p += 256) {
    float v = ps[b*PPB + p];
    if (v > bv || (v == bv && p < bi)) { bv = v; bi = p; }
  }
  sv[t] = bv; si[t] = bi; __syncthreads();
  for (int s = 128; s; s >>= 1) {
    if (t < s) {
      if (sv[t+s] > sv[t] || (sv[t+s] == sv[t] && si[t+s] < si[t])) { sv[t] = sv[t+s]; si[t] = si[t+s]; }
    }
    __syncthreads();
  }
  if (t == 0) {
    bscore[b] = sv[0];
    brow[b]   = b*PPB + si[0];
    bnn[b]    = loc[b*PPB + si[0]];
  }
}

// one pass over the bank, all 8 batches per row (bank read once)
__global__ __launch_bounds__(256) void dbank_kernel(
    const float* __restrict__ bank, const float* __restrict__ yn,
    const int* __restrict__ bnn, float* __restrict__ dbank)
{
  __shared__ float xs[8][EDIM];
  int t = threadIdx.x;
  for (int idx = t*4; idx < 8*EDIM; idx += 256*4) {
    int b = idx / EDIM, k = idx % EDIM;
    float4 v = *reinterpret_cast<const float4*>(bank + (size_t)bnn[b]*EDIM + k);
    *reinterpret_cast<float4*>(&xs[b][k]) = v;
  }
  __syncthreads();
  int m = blockIdx.x*4 + (t >> 6);
  if (m >= MBANK) return;
  int lane = t & 63;
  const float4* yp = reinterpret_cast<const float4*>(bank + (size_t)m*EDIM);
  float acc[8] = {0.f,0.f,0.f,0.f,0.f,0.f,0.f,0.f};
  for (int k4 = lane; k4 < EDIM/4; k4 += 64) {
    float4 y = yp[k4];
    int k = k4*4;
    #pragma unroll
    for (int b = 0; b < 8; ++b) {
      acc[b] = fmaf(y.x, xs[b][k+0], acc[b]);
      acc[b] = fmaf(y.y, xs[b][k+1], acc[b]);
      acc[b] = fmaf(y.z, xs[b][k+2], acc[b]);
      acc[b] = fmaf(y.w, xs[b][k+3], acc[b]);
    }
  }
  #pragma unroll
  for (int b = 0; b < 8; ++b) {
    float a = acc[b];
    #pragma unroll
    for (int s = 32; s; s >>= 1) a += __shfl_xor(a, s);
    acc[b] = a;
  }
  if (lane == 0) {
    #pragma unroll
    for (int b = 0; b < 8; ++b) {
      int nn = bnn[b];
      float d2 = yn[nn] - 2.f*acc[b] + yn[m];
      dbank[(size_t)b*MBANK + m] = sqrtf(fmaxf(d2, 0.f));
    }
  }
}

__global__ void top9_kernel(float* __restrict__ dbank, int* __restrict__ support) {
  __shared__ float sv[256]; __shared__ int si[256];
  int b = blockIdx.x, t = threadIdx.x;
  float* db = dbank + (size_t)b*MBANK;
  for (int r = 0; r < NNB; ++r) {
    float bv = INFINITY; int bi = 0x7fffffff;
    for (int m = t; m < MBANK; m += 256) {
      float v = db[m];
      if (v < bv || (v == bv && m < bi)) { bv = v; bi = m; }
    }
    sv[t] = bv; si[t] = bi; __syncthreads();
    for (int s = 128; s; s >>= 1) {
      if (t < s) {
        if (sv[t+s] < sv[t] || (sv[t+s] == sv[t] && si[t+s] < si[t])) { sv[t] = sv[t+s]; si[t] = si[t+s]; }
      }
      __syncthreads();
    }
    if (t == 0) { support[b*NNB + r] = si[0]; db[si[0]] = INFINITY; }
    __syncthreads();
  }
}

__global__ void dsup_kernel(const unsigned short* __restrict__ embb, const float* __restrict__ bank,
                            const float* __restrict__ xn, const float* __restrict__ yn,
                            const int* __restrict__ brow, const int* __restrict__ support,
                            float* __restrict__ dsup) {
  int w = (blockIdx.x*blockDim.x + threadIdx.x) >> 6;
  int lane = threadIdx.x & 63;
  if (w >= NB*NNB) return;
  int b = w / NNB, j = w % NNB;
  int row = brow[b]; int sup = support[b*NNB + j];
  const unsigned short* x = embb + (size_t)row*EDIM;
  const float* y = bank + (size_t)sup*EDIM;
  float acc = 0.f;
  for (int k = lane; k < EDIM; k += 64) acc = fmaf(bf2f(x[k]), y[k], acc);
  #pragma unroll
  for (int s = 32; s; s >>= 1) acc += __shfl_xor(acc, s);
  if (lane == 0) dsup[b*NNB + j] = sqrtf(fmaxf(xn[row] - 2.f*acc + yn[sup], 0.f));
}

__global__ void pred_kernel(const float* __restrict__ dsup, const float* __restrict__ bscore,
                            float* __restrict__ out) {
  int b = threadIdx.x;
  if (b >= NB) return;
  float d[NNB]; float mx = -INFINITY;
  #pragma unroll
  for (int j = 0; j < NNB; ++j) { d[j] = dsup[b*NNB + j]; mx = fmaxf(mx, d[j]); }
  float s = 0.f;
  #pragma unroll
  for (int j = 0; j < NNB; ++j) s += expf(d[j] - mx);
  float w = 1.f - expf(d[0] - mx) / s;
  out[b] = w * bscore[b];
}

// ---------------- anomaly map ----------------

__global__ void gk_kernel(float* __restrict__ gk) {
  if (threadIdx.x == 0 && blockIdx.x == 0) {
    float w[KS]; float s = 0.f;
    for (int t = 0; t < KS; ++t) {
      float x = (float)t - (float)KR;
      w[t] = expf(-(x*x) / (2.f*4.f*4.f));
      s += w[t];
    }
    for (int t = 0; t < KS; ++t) gk[t] = w[t] / s;
  }
}

__global__ void upmap_kernel(const float* __restrict__ ps, float* __restrict__ amap) {
  int id = blockIdx.x*blockDim.x + threadIdx.x;
  if (id >= NB*OUTW*OUTW) return;
  int j = id % OUTW, i = (id/OUTW) % OUTW, b = id/(OUTW*OUTW);
  float sy = ((float)i + 0.5f)*0.125f - 0.5f; sy = fminf(fmaxf(sy,0.f),(float)(H2-1));
  int y0 = (int)sy; int y1 = min(y0+1,H2-1); float fy = sy - (float)y0;
  float sx = ((float)j + 0.5f)*0.125f - 0.5f; sx = fminf(fmaxf(sx,0.f),(float)(W2-1));
  int x0 = (int)sx; int x1 = min(x0+1,W2-1); float fx = sx - (float)x0;
  const float* p = ps + b*PPB;
  amap[id] = (1.f-fy)*((1.f-fx)*p[y0*W2+x0] + fx*p[y0*W2+x1])
           +      fy *((1.f-fx)*p[y1*W2+x0] + fx*p[y1*W2+x1]);
}

__device__ __forceinline__ int refl224(int x) {
  if (x < 0) return -x;
  if (x > OUTW-1) return 2*(OUTW-1) - x;
  return x;
}

__global__ void blurh_kernel(const float* __restrict__ in, const float* __restrict__ gk,
                             float* __restrict__ out) {
  int id = blockIdx.x*blockDim.x + threadIdx.x;
  if (id >= NB*OUTW*OUTW) return;
  int j = id % OUTW;
  int base = id - j;
  float s = 0.f;
  #pragma unroll
  for (int v = 0; v < KS; ++v) {
    int jj = refl224(j - KR + v);
    s = fmaf(gk[v], in[base + jj], s);
  }
  out[id] = s;
}

__global__ void blurv_kernel(const float* __restrict__ in, const float* __restrict__ gk,
                             float* __restrict__ out) {
  int id = blockIdx.x*blockDim.x + threadIdx.x;
  if (id >= NB*OUTW*OUTW) return;
  int j = id % OUTW, i = (id/OUTW) % OUTW, b = id/(OUTW*OUTW);
  float s = 0.f;
  #pragma unroll
  for (int u = 0; u < KS; ++u) {
    int ii = refl224(i - KR + u);
    s = fmaf(gk[u], in[((size_t)b*OUTW + ii)*OUTW + j], s);
  }
  out[id] = s;
}

// ---------------- launch ----------------

extern "C" void kernel_launch(void* const* d_in, const int* in_sizes, int n_in,
                              void* d_out, int out_size, void* d_ws, size_t ws_size,
                              hipStream_t stream) {
  const float* feat2 = (const float*)d_in[0];
  const float* feat3 = (const float*)d_in[1];
  const float* bank  = (const float*)d_in[2];
  float* out = (float*)d_out;

  char* base = (char*)d_ws;
  size_t off = 0;
  auto alloc = [&](size_t nbytes) -> char* {
    char* p = base + off;
    off += ((nbytes + 255) & ~(size_t)255);
    return p;
  };
  unsigned short* embb  = (unsigned short*)alloc((size_t)NPATCH*EDIM*2);
  unsigned short* bankb = (unsigned short*)alloc((size_t)MBANK*EDIM*2);
  float* f3p    = (float*)alloc((size_t)NB*C3*H3*W3*4);
  float* yn     = (float*)alloc(MBANK*4);
  float* xn     = (float*)alloc(NPATCH*4);
  float* wsminv = (float*)alloc((size_t)NPATCH*NSPLIT*4);
  int*   wsargi = (int*)  alloc((size_t)NPATCH*NSPLIT*4);
  float* ps     = (float*)alloc(NPATCH*4);
  int*   loc    = (int*)  alloc(NPATCH*4);
  float* bscore = (float*)alloc(NB*4);
  int*   brow   = (int*)  alloc(NB*4);
  int*   bnn    = (int*)  alloc(NB*4);
  float* dbank  = (float*)alloc((size_t)NB*MBANK*4);
  int*   supp   = (int*)  alloc(NB*NNB*4);
  float* dsup   = (float*)alloc(NB*NNB*4);
  float* gk     = (float*)alloc(KS*4);
  float* amap   = (float*)alloc((size_t)NB*OUTW*OUTW*4);
  float* tmp    = (float*)alloc((size_t)NB*OUTW*OUTW*4);

  gk_kernel<<<1, 64, 0, stream>>>(gk);

  {
    int n = NB*C2*H2*W2;
    pool2_kernel<<<(n+255)/256, 256, 0, stream>>>(feat2, embb);
  }
  {
    int n = NB*C3*H3*W3;
    pool3_kernel<<<(n+255)/256, 256, 0, stream>>>(feat3, f3p);
  }
  {
    int n = NB*C3*H2*W2;
    up3_kernel<<<(n+255)/256, 256, 0, stream>>>(f3p, embb);
  }
  {
    int n4 = MBANK*EDIM/4;
    tobf16_kernel<<<(n4+255)/256, 256, 0, stream>>>(bank, bankb, n4);
  }
  norm_kernel<<<(MBANK*64+255)/256, 256, 0, stream>>>(bank, yn, MBANK);
  norm_bf16_kernel<<<(NPATCH*64+255)/256, 256, 0, stream>>>(embb, xn, NPATCH);

  {
    dim3 grid(NSPLIT, NPATCH/128);
    dist_min_mfma<<<grid, 256, 0, stream>>>(embb, bankb, xn, yn, wsminv, wsargi);
  }
  reduce_min_kernel<<<(NPATCH+255)/256, 256, 0, stream>>>(wsminv, wsargi, ps, loc);

  argmax_kernel<<<NB, 256, 0, stream>>>(ps, loc, bscore, brow, bnn);
  dbank_kernel<<<MBANK/4, 256, 0, stream>>>(bank, yn, bnn, dbank);
  top9_kernel<<<NB, 256, 0, stream>>>(dbank, supp);
  dsup_kernel<<<(NB*NNB*64 + 255)/256, 256, 0, stream>>>(embb, bank, xn, yn, brow, supp, dsup);
  pred_kernel<<<1, 64, 0, stream>>>(dsup, bscore, out + NB*OUTW*OUTW);

  {
    int n = NB*OUTW*OUTW;
    upmap_kernel<<<(n+255)/256, 256, 0, stream>>>(ps, amap);
    blurh_kernel<<<(n+255)/256, 256, 0, stream>>>(amap, gk, tmp);
    blurv_kernel<<<(n+255)/256, 256, 0, stream>>>(tmp, gk, out);
  }
}

// Round 3
// 727.308 us; speedup vs baseline: 9.3558x; 1.2729x over previous
//
#include <hip/hip_runtime.h>
#include <math.h>

#define NB 8
#define C2 512
#define C3 1024
#define H2 28
#define W2 28
#define H3 14
#define W3 14
#define EDIM 1536
#define PPB (H2*W2)            /* 784 */
#define NPATCH (NB*PPB)        /* 6272 */
#define MBANK 20000
#define OUTW 224
#define NNB 9
#define KS 33
#define KR 16
#define NSPLIT 32
#define NT_N (NPATCH/128)          /* 49 */
#define NTILE ((MBANK + 127)/128)  /* 157 */
#define KTILES (EDIM/64)           /* 24 */
#define CHUNKS 8
#define CH (MBANK/CHUNKS)          /* 2500 */

typedef __attribute__((ext_vector_type(8))) short short8;
typedef __attribute__((ext_vector_type(4))) float f32x4;

#define LEXLT(va,ia,vb,ib) ((va) < (vb) || ((va)==(vb) && (ia)<(ib)))
#define CSWAP(va,ia,vb,ib) { if (LEXLT(va,ia,vb,ib)) { float _tv=(vb); int _ti=(ib); (vb)=(va); (ib)=(ia); (va)=_tv; (ia)=_ti; } }

__device__ __forceinline__ float bf2f(unsigned short u) {
  union { unsigned u; float f; } c; c.u = ((unsigned)u) << 16; return c.f;
}
__device__ __forceinline__ unsigned short f2bf(float f) {
  union { float f; unsigned u; } c; c.f = f;
  unsigned r = c.u + 0x7fff + ((c.u >> 16) & 1);
  return (unsigned short)(r >> 16);
}
__device__ __forceinline__ void gload16(const void* g, void* l) {
  __builtin_amdgcn_global_load_lds(
      (const __attribute__((address_space(1))) unsigned int*)g,
      (__attribute__((address_space(3))) unsigned int*)l, 16, 0, 0);
}

// ---------------- feature pooling / embedding (emb stored bf16) ----------------

__global__ void pool2_kernel(const float* __restrict__ in, unsigned short* __restrict__ emb) {
  int id = blockIdx.x*blockDim.x + threadIdx.x;
  if (id >= NB*C2*H2*W2) return;
  int w = id % W2, h = (id / W2) % H2, c = (id / (H2*W2)) % C2, b = id / (C2*H2*W2);
  const float* src = in + (size_t)(b*C2 + c)*H2*W2;
  float s = 0.f;
  #pragma unroll
  for (int dh=-1; dh<=1; ++dh) {
    int hh = h+dh; if (hh<0||hh>=H2) continue;
    #pragma unroll
    for (int dw=-1; dw<=1; ++dw) {
      int ww = w+dw; if (ww<0||ww>=W2) continue;
      s += src[hh*W2+ww];
    }
  }
  emb[((size_t)(b*PPB) + h*W2 + w)*EDIM + c] = f2bf(s * (1.f/9.f));
}

__global__ void pool3_kernel(const float* __restrict__ in, float* __restrict__ f3p) {
  int id = blockIdx.x*blockDim.x + threadIdx.x;
  if (id >= NB*C3*H3*W3) return;
  int w = id % W3, h = (id / W3) % H3, c = (id / (H3*W3)) % C3, b = id / (C3*H3*W3);
  const float* src = in + (size_t)(b*C3 + c)*H3*W3;
  float s = 0.f;
  #pragma unroll
  for (int dh=-1; dh<=1; ++dh) {
    int hh = h+dh; if (hh<0||hh>=H3) continue;
    #pragma unroll
    for (int dw=-1; dw<=1; ++dw) {
      int ww = w+dw; if (ww<0||ww>=W3) continue;
      s += src[hh*W3+ww];
    }
  }
  f3p[(size_t)id] = s * (1.f/9.f);
}

__global__ void up3_kernel(const float* __restrict__ f3p, unsigned short* __restrict__ emb) {
  int id = blockIdx.x*blockDim.x + threadIdx.x;
  if (id >= NB*C3*H2*W2) return;
  int j = id % W2, i = (id/W2)%H2, c = (id/(H2*W2))%C3, b = id/(C3*H2*W2);
  float sy = i*0.5f - 0.25f; sy = fminf(fmaxf(sy,0.f),(float)(H3-1));
  int y0 = (int)sy; int y1 = min(y0+1,H3-1); float fy = sy - (float)y0;
  float sx = j*0.5f - 0.25f; sx = fminf(fmaxf(sx,0.f),(float)(W3-1));
  int x0 = (int)sx; int x1 = min(x0+1,W3-1); float fx = sx - (float)x0;
  const float* p = f3p + (size_t)(b*C3+c)*H3*W3;
  float v = (1.f-fy)*((1.f-fx)*p[y0*W3+x0] + fx*p[y0*W3+x1])
          +      fy *((1.f-fx)*p[y1*W3+x0] + fx*p[y1*W3+x1]);
  emb[((size_t)(b*PPB) + i*W2 + j)*EDIM + C2 + c] = f2bf(v);
}

// ---------------- bank prep: fp32 -> bf16 + norms in one pass ----------------

__global__ void bank_prep_kernel(const float* __restrict__ bank, unsigned short* __restrict__ bankb,
                                 float* __restrict__ yn) {
  int w = (blockIdx.x*blockDim.x + threadIdx.x) >> 6;
  int lane = threadIdx.x & 63;
  if (w >= MBANK) return;
  const float4* p = reinterpret_cast<const float4*>(bank + (size_t)w*EDIM);
  ushort4* q = reinterpret_cast<ushort4*>(bankb + (size_t)w*EDIM);
  float acc = 0.f;
  #pragma unroll
  for (int k = 0; k < EDIM/4/64; ++k) {
    int k4 = lane + k*64;
    float4 v = p[k4];
    acc = fmaf(v.x,v.x,acc); acc = fmaf(v.y,v.y,acc);
    acc = fmaf(v.z,v.z,acc); acc = fmaf(v.w,v.w,acc);
    ushort4 o; o.x = f2bf(v.x); o.y = f2bf(v.y); o.z = f2bf(v.z); o.w = f2bf(v.w);
    q[k4] = o;
  }
  #pragma unroll
  for (int s = 32; s; s >>= 1) acc += __shfl_xor(acc, s);
  if (lane == 0) yn[w] = acc;
}

__global__ void norm_bf16_kernel(const unsigned short* __restrict__ src, float* __restrict__ norms, int rows) {
  int w = (blockIdx.x*blockDim.x + threadIdx.x) >> 6;
  int lane = threadIdx.x & 63;
  if (w >= rows) return;
  const ushort4* p = reinterpret_cast<const ushort4*>(src + (size_t)w*EDIM);
  float acc = 0.f;
  for (int k = lane; k < EDIM/4; k += 64) {
    ushort4 v = p[k];
    float a = bf2f(v.x), b = bf2f(v.y), c = bf2f(v.z), d = bf2f(v.w);
    acc = fmaf(a,a,acc); acc = fmaf(b,b,acc); acc = fmaf(c,c,acc); acc = fmaf(d,d,acc);
  }
  #pragma unroll
  for (int s = 32; s; s >>= 1) acc += __shfl_xor(acc, s);
  if (lane == 0) norms[w] = acc;
}

// ---------------- fused bf16-MFMA distance GEMM + min/argmin ----------------
// 128x128 tile, BK=64, 4 waves. XOR-swizzled LDS (pre-swizzled global src,
// swizzled ds_read). 1D grid with XCD swizzle: blocks sharing a split (same
// bank range, ~1.9MB) land on the same XCD for L2 reuse.

__global__ __launch_bounds__(256, 2) void dist_min_mfma(
    const unsigned short* __restrict__ A, const unsigned short* __restrict__ B,
    const float* __restrict__ xn, const float* __restrict__ yn,
    float* __restrict__ outv, int* __restrict__ outi)
{
  __shared__ __align__(16) unsigned char AsB[16384];
  __shared__ __align__(16) unsigned char BsB[16384];
  const int t = threadIdx.x;
  const int lane = t & 63, wid = t >> 6;
  const int wr = wid >> 1, wc = wid & 1;

  const int bid = blockIdx.x;
  const int sid = bid & 7, rest = bid >> 3;
  const int ntile = rest % NT_N, g = rest / NT_N;
  const int split = sid + 8*g;
  const int n0 = ntile * 128;
  const int mt_begin = (split * NTILE) / NSPLIT;
  const int mt_end   = ((split + 1) * NTILE) / NSPLIT;

  const int gch = (lane & 7) ^ (lane >> 3);
  const char* aSrc[4];
  #pragma unroll
  for (int q = 0; q < 4; ++q) {
    int ar = n0 + wid*32 + q*8 + (lane >> 3);
    aSrc[q] = (const char*)A + ((size_t)ar*EDIM + gch*8)*2;
  }
  char* aDst = (char*)AsB + wid*4096;
  char* bDst = (char*)BsB + wid*4096;

  const int abase = (wr*64 + (lane & 15)) * 128;
  const int bbase = (wc*64 + (lane & 15)) * 128;
  const int koff0 = (((lane >> 4)    ) ^ (lane & 7)) * 16;
  const int koff1 = (((lane >> 4) + 4) ^ (lane & 7)) * 16;

  float bq[4][4]; int bi[4][4];
  #pragma unroll
  for (int fi = 0; fi < 4; ++fi)
    #pragma unroll
    for (int r = 0; r < 4; ++r) { bq[fi][r] = INFINITY; bi[fi][r] = 0x7fffffff; }

  for (int mt = mt_begin; mt < mt_end; ++mt) {
    const int m0 = mt * 128;
    const char* bSrc[4];
    #pragma unroll
    for (int q = 0; q < 4; ++q) {
      int br = m0 + wid*32 + q*8 + (lane >> 3);
      if (br > MBANK-1) br = MBANK-1;
      bSrc[q] = (const char*)B + ((size_t)br*EDIM + gch*8)*2;
    }

    f32x4 acc[4][4];
    #pragma unroll
    for (int fi = 0; fi < 4; ++fi)
      #pragma unroll
      for (int fj = 0; fj < 4; ++fj) acc[fi][fj] = (f32x4){0.f,0.f,0.f,0.f};

    for (int kt = 0; kt < KTILES; ++kt) {
      const int kb = kt * 128;
      __syncthreads();
      #pragma unroll
      for (int q = 0; q < 4; ++q) gload16(aSrc[q] + kb, aDst + q*1024);
      #pragma unroll
      for (int q = 0; q < 4; ++q) gload16(bSrc[q] + kb, bDst + q*1024);
      __syncthreads();
      #pragma unroll
      for (int ks = 0; ks < 2; ++ks) {
        const int ko = ks ? koff1 : koff0;
        short8 af[4], bfr[4];
        #pragma unroll
        for (int fi = 0; fi < 4; ++fi)
          af[fi] = *reinterpret_cast<const short8*>(AsB + abase + fi*2048 + ko);
        #pragma unroll
        for (int fj = 0; fj < 4; ++fj)
          bfr[fj] = *reinterpret_cast<const short8*>(BsB + bbase + fj*2048 + ko);
        #pragma unroll
        for (int fi = 0; fi < 4; ++fi)
          #pragma unroll
          for (int fj = 0; fj < 4; ++fj)
            acc[fi][fj] = __builtin_amdgcn_mfma_f32_16x16x32_bf16(af[fi], bfr[fj], acc[fi][fj], 0, 0, 0);
      }
    }

    #pragma unroll
    for (int fj = 0; fj < 4; ++fj) {
      int col = m0 + wc*64 + fj*16 + (lane & 15);
      float ynv = (col < MBANK) ? yn[col] : INFINITY;
      #pragma unroll
      for (int fi = 0; fi < 4; ++fi)
        #pragma unroll
        for (int r = 0; r < 4; ++r) {
          float q = fmaf(-2.f, acc[fi][fj][r], ynv);
          if (q < bq[fi][r] || (q == bq[fi][r] && col < bi[fi][r])) {
            bq[fi][r] = q; bi[fi][r] = col;
          }
        }
    }
  }

  __syncthreads();
  float* sv = (float*)AsB;  // [128][2]
  int*   si = (int*)BsB;
  #pragma unroll
  for (int fi = 0; fi < 4; ++fi)
    #pragma unroll
    for (int r = 0; r < 4; ++r) {
      float v = bq[fi][r]; int ix = bi[fi][r];
      #pragma unroll
      for (int m = 1; m < 16; m <<= 1) {
        float ov = __shfl_xor(v, m);
        int   oi = __shfl_xor(ix, m);
        if (ov < v || (ov == v && oi < ix)) { v = ov; ix = oi; }
      }
      if ((lane & 15) == 0) {
        int rl = wr*64 + fi*16 + (lane >> 4)*4 + r;
        sv[rl*2 + wc] = v; si[rl*2 + wc] = ix;
      }
    }
  __syncthreads();
  if (t < 128) {
    float q0 = sv[t*2], q1 = sv[t*2+1];
    int   i0 = si[t*2], i1 = si[t*2+1];
    float q; int ix;
    if (q1 < q0 || (q1 == q0 && i1 < i0)) { q = q1; ix = i1; } else { q = q0; ix = i0; }
    int row = n0 + t;
    float d = sqrtf(fmaxf(xn[row] + q, 0.f));
    outv[(size_t)row * NSPLIT + split] = d;
    outi[(size_t)row * NSPLIT + split] = ix;
  }
}

__global__ void reduce_min_kernel(const float* __restrict__ outv, const int* __restrict__ outi,
                                  float* __restrict__ ps, int* __restrict__ loc) {
  int r = blockIdx.x*blockDim.x + threadIdx.x;
  if (r >= NPATCH) return;
  float bv = INFINITY; int bi = 0x7fffffff;
  for (int s = 0; s < NSPLIT; ++s) {
    float v = outv[(size_t)r*NSPLIT + s];
    int  ix = outi[(size_t)r*NSPLIT + s];
    if (v < bv || (v == bv && ix < bi)) { bv = v; bi = ix; }
  }
  ps[r] = bv; loc[r] = bi;
}

// ---------------- anomaly score ----------------

__global__ void argmax_kernel(const float* __restrict__ ps, const int* __restrict__ loc,
                              float* __restrict__ bscore, int* __restrict__ brow, int* __restrict__ bnn) {
  __shared__ float sv[256]; __shared__ int si[256];
  int b = blockIdx.x, t = threadIdx.x;
  float bv = -INFINITY; int bi = 0x7fffffff;
  for (int p = t; p < PPB; p += 256) {
    float v = ps[b*PPB + p];
    if (v > bv || (v == bv && p < bi)) { bv = v; bi = p; }
  }
  sv[t] = bv; si[t] = bi; __syncthreads();
  for (int s = 128; s; s >>= 1) {
    if (t < s) {
      if (sv[t+s] > sv[t] || (sv[t+s] == sv[t] && si[t+s] < si[t])) { sv[t] = sv[t+s]; si[t] = si[t+s]; }
    }
    __syncthreads();
  }
  if (t == 0) {
    bscore[b] = sv[0];
    brow[b]   = b*PPB + si[0];
    bnn[b]    = loc[b*PPB + si[0]];
  }
}

// one pass over the fp32 bank, all 8 batches per row
__global__ __launch_bounds__(256) void dbank_kernel(
    const float* __restrict__ bank, const float* __restrict__ yn,
    const int* __restrict__ bnn, float* __restrict__ dbank)
{
  __shared__ float xs[8][EDIM];
  int t = threadIdx.x;
  for (int idx = t*4; idx < 8*EDIM; idx += 256*4) {
    int b = idx / EDIM, k = idx % EDIM;
    float4 v = *reinterpret_cast<const float4*>(bank + (size_t)bnn[b]*EDIM + k);
    *reinterpret_cast<float4*>(&xs[b][k]) = v;
  }
  __syncthreads();
  int m = blockIdx.x*4 + (t >> 6);
  if (m >= MBANK) return;
  int lane = t & 63;
  const float4* yp = reinterpret_cast<const float4*>(bank + (size_t)m*EDIM);
  float acc[8] = {0.f,0.f,0.f,0.f,0.f,0.f,0.f,0.f};
  for (int k4 = lane; k4 < EDIM/4; k4 += 64) {
    float4 y = yp[k4];
    int k = k4*4;
    #pragma unroll
    for (int b = 0; b < 8; ++b) {
      acc[b] = fmaf(y.x, xs[b][k+0], acc[b]);
      acc[b] = fmaf(y.y, xs[b][k+1], acc[b]);
      acc[b] = fmaf(y.z, xs[b][k+2], acc[b]);
      acc[b] = fmaf(y.w, xs[b][k+3], acc[b]);
    }
  }
  #pragma unroll
  for (int b = 0; b < 8; ++b) {
    float a = acc[b];
    #pragma unroll
    for (int s = 32; s; s >>= 1) a += __shfl_xor(a, s);
    acc[b] = a;
  }
  if (lane == 0) {
    #pragma unroll
    for (int b = 0; b < 8; ++b) {
      int nn = bnn[b];
      float d2 = yn[nn] - 2.f*acc[b] + yn[m];
      dbank[(size_t)b*MBANK + m] = sqrtf(fmaxf(d2, 0.f));
    }
  }
}

// ---------------- parallel top-9: stage 1 (per-chunk) ----------------

__global__ __launch_bounds__(256) void top9_stage1(const float* __restrict__ dbank,
                                                   float* __restrict__ cv, int* __restrict__ ci) {
  int b = blockIdx.x / CHUNKS, ch = blockIdx.x % CHUNKS;
  const float* db = dbank + (size_t)b*MBANK + ch*CH;
  int t = threadIdx.x;

  float v0=INFINITY,v1=INFINITY,v2=INFINITY,v3=INFINITY,v4=INFINITY,
        v5=INFINITY,v6=INFINITY,v7=INFINITY,v8=INFINITY;
  int i0=0x7fffffff,i1=0x7fffffff,i2=0x7fffffff,i3=0x7fffffff,i4=0x7fffffff,
      i5=0x7fffffff,i6=0x7fffffff,i7=0x7fffffff,i8=0x7fffffff;

  for (int s = 0; s < (CH+255)/256; ++s) {
    int m = t + s*256;
    if (m < CH) {
      float nv = db[m]; int ni = ch*CH + m;
      if (LEXLT(nv,ni,v8,i8)) {
        v8 = nv; i8 = ni;
        CSWAP(v8,i8,v7,i7); CSWAP(v7,i7,v6,i6); CSWAP(v6,i6,v5,i5); CSWAP(v5,i5,v4,i4);
        CSWAP(v4,i4,v3,i3); CSWAP(v3,i3,v2,i2); CSWAP(v2,i2,v1,i1); CSWAP(v1,i1,v0,i0);
      }
    }
  }

  __shared__ float sv[256*9];
  __shared__ int   si[256*9];
  __shared__ float rv[256]; __shared__ int ri[256]; __shared__ int rp[256];
  sv[t*9+0]=v0; sv[t*9+1]=v1; sv[t*9+2]=v2; sv[t*9+3]=v3; sv[t*9+4]=v4;
  sv[t*9+5]=v5; sv[t*9+6]=v6; sv[t*9+7]=v7; sv[t*9+8]=v8;
  si[t*9+0]=i0; si[t*9+1]=i1; si[t*9+2]=i2; si[t*9+3]=i3; si[t*9+4]=i4;
  si[t*9+5]=i5; si[t*9+6]=i6; si[t*9+7]=i7; si[t*9+8]=i8;
  __syncthreads();

  for (int r = 0; r < NNB; ++r) {
    float bv = INFINITY; int bix = 0x7fffffff; int bp = -1;
    #pragma unroll
    for (int u = 0; u < 9; ++u) {
      float v = sv[t*9+u]; int ix = si[t*9+u];
      if (LEXLT(v,ix,bv,bix)) { bv = v; bix = ix; bp = t*9+u; }
    }
    rv[t] = bv; ri[t] = bix; rp[t] = bp; __syncthreads();
    for (int s = 128; s; s >>= 1) {
      if (t < s) {
        if (LEXLT(rv[t+s],ri[t+s],rv[t],ri[t])) { rv[t]=rv[t+s]; ri[t]=ri[t+s]; rp[t]=rp[t+s]; }
      }
      __syncthreads();
    }
    if (t == 0) {
      cv[blockIdx.x*NNB + r] = rv[0];
      ci[blockIdx.x*NNB + r] = ri[0];
      sv[rp[0]] = INFINITY; si[rp[0]] = 0x7fffffff;
    }
    __syncthreads();
  }
}

// ---------------- top-9: stage 2 (merge 8 chunks x 9) ----------------

__global__ void top9_stage2(const float* __restrict__ cv, const int* __restrict__ ci,
                            int* __restrict__ support) {
  __shared__ float sv[128]; __shared__ int si[128];
  __shared__ float wv[128]; __shared__ int wi[128]; __shared__ int wp[128];
  int b = blockIdx.x, t = threadIdx.x;
  if (t < CHUNKS*NNB) { sv[t] = cv[b*CHUNKS*NNB + t]; si[t] = ci[b*CHUNKS*NNB + t]; }
  else { sv[t] = INFINITY; si[t] = 0x7fffffff; }
  __syncthreads();
  for (int r = 0; r < NNB; ++r) {
    wv[t] = sv[t]; wi[t] = si[t]; wp[t] = t; __syncthreads();
    for (int s = 64; s; s >>= 1) {
      if (t < s) {
        if (LEXLT(wv[t+s],wi[t+s],wv[t],wi[t])) { wv[t]=wv[t+s]; wi[t]=wi[t+s]; wp[t]=wp[t+s]; }
      }
      __syncthreads();
    }
    if (t == 0) {
      support[b*NNB + r] = wi[0];
      sv[wp[0]] = INFINITY; si[wp[0]] = 0x7fffffff;
    }
    __syncthreads();
  }
}

__global__ void dsup_kernel(const unsigned short* __restrict__ embb, const float* __restrict__ bank,
                            const float* __restrict__ xn, const float* __restrict__ yn,
                            const int* __restrict__ brow, const int* __restrict__ support,
                            float* __restrict__ dsup) {
  int w = (blockIdx.x*blockDim.x + threadIdx.x) >> 6;
  int lane = threadIdx.x & 63;
  if (w >= NB*NNB) return;
  int b = w / NNB, j = w % NNB;
  int row = brow[b]; int sup = support[b*NNB + j];
  const unsigned short* x = embb + (size_t)row*EDIM;
  const float* y = bank + (size_t)sup*EDIM;
  float acc = 0.f;
  for (int k = lane; k < EDIM; k += 64) acc = fmaf(bf2f(x[k]), y[k], acc);
  #pragma unroll
  for (int s = 32; s; s >>= 1) acc += __shfl_xor(acc, s);
  if (lane == 0) dsup[b*NNB + j] = sqrtf(fmaxf(xn[row] - 2.f*acc + yn[sup], 0.f));
}

__global__ void pred_kernel(const float* __restrict__ dsup, const float* __restrict__ bscore,
                            float* __restrict__ out) {
  int b = threadIdx.x;
  if (b >= NB) return;
  float d[NNB]; float mx = -INFINITY;
  #pragma unroll
  for (int j = 0; j < NNB; ++j) { d[j] = dsup[b*NNB + j]; mx = fmaxf(mx, d[j]); }
  float s = 0.f;
  #pragma unroll
  for (int j = 0; j < NNB; ++j) s += expf(d[j] - mx);
  float w = 1.f - expf(d[0] - mx) / s;
  out[b] = w * bscore[b];
}

// ---------------- anomaly map ----------------

__global__ void gk_kernel(float* __restrict__ gk) {
  if (threadIdx.x == 0 && blockIdx.x == 0) {
    float w[KS]; float s = 0.f;
    for (int t = 0; t < KS; ++t) {
      float x = (float)t - (float)KR;
      w[t] = expf(-(x*x) / (2.f*4.f*4.f));
      s += w[t];
    }
    for (int t = 0; t < KS; ++t) gk[t] = w[t] / s;
  }
}

__device__ __forceinline__ int refl224(int x) {
  if (x < 0) return -x;
  if (x > OUTW-1) return 2*(OUTW-1) - x;
  return x;
}

// fused: bilinear-upsample one output row (28->224 in y done via 2-row lerp,
// x on the fly) + horizontal gaussian pass
__global__ __launch_bounds__(256) void upblurh_kernel(const float* __restrict__ ps,
                                                      const float* __restrict__ gk,
                                                      float* __restrict__ tmp) {
  int b = blockIdx.x / OUTW, i = blockIdx.x % OUTW;
  int t = threadIdx.x;
  __shared__ float l[W2];
  __shared__ float gks[KS];
  if (t < KS) gks[t] = gk[t];
  float sy = ((float)i + 0.5f)*0.125f - 0.5f; sy = fminf(fmaxf(sy,0.f),(float)(H2-1));
  int y0 = (int)sy; int y1 = min(y0+1,H2-1); float fy = sy - (float)y0;
  if (t < W2) {
    const float* p = ps + b*PPB;
    l[t] = (1.f-fy)*p[y0*W2+t] + fy*p[y1*W2+t];
  }
  __syncthreads();
  if (t >= OUTW) return;
  float s = 0.f;
  #pragma unroll
  for (int v = 0; v < KS; ++v) {
    int jj = refl224(t - KR + v);
    float sx = ((float)jj + 0.5f)*0.125f - 0.5f; sx = fminf(fmaxf(sx,0.f),(float)(W2-1));
    int x0 = (int)sx; int x1 = min(x0+1,W2-1); float fx = sx - (float)x0;
    s = fmaf(gks[v], (1.f-fx)*l[x0] + fx*l[x1], s);
  }
  tmp[((size_t)b*OUTW + i)*OUTW + t] = s;
}

__global__ void blurv_kernel(const float* __restrict__ in, const float* __restrict__ gk,
                             float* __restrict__ out) {
  int id = blockIdx.x*blockDim.x + threadIdx.x;
  if (id >= NB*OUTW*OUTW) return;
  int j = id % OUTW, i = (id/OUTW) % OUTW, b = id/(OUTW*OUTW);
  float s = 0.f;
  #pragma unroll
  for (int u = 0; u < KS; ++u) {
    int ii = refl224(i - KR + u);
    s = fmaf(gk[u], in[((size_t)b*OUTW + ii)*OUTW + j], s);
  }
  out[id] = s;
}

// ---------------- launch ----------------

extern "C" void kernel_launch(void* const* d_in, const int* in_sizes, int n_in,
                              void* d_out, int out_size, void* d_ws, size_t ws_size,
                              hipStream_t stream) {
  const float* feat2 = (const float*)d_in[0];
  const float* feat3 = (const float*)d_in[1];
  const float* bank  = (const float*)d_in[2];
  float* out = (float*)d_out;

  char* base = (char*)d_ws;
  size_t off = 0;
  auto alloc = [&](size_t nbytes) -> char* {
    char* p = base + off;
    off += ((nbytes + 255) & ~(size_t)255);
    return p;
  };
  unsigned short* embb  = (unsigned short*)alloc((size_t)NPATCH*EDIM*2);
  unsigned short* bankb = (unsigned short*)alloc((size_t)MBANK*EDIM*2);
  float* f3p    = (float*)alloc((size_t)NB*C3*H3*W3*4);
  float* yn     = (float*)alloc(MBANK*4);
  float* xn     = (float*)alloc(NPATCH*4);
  float* wsminv = (float*)alloc((size_t)NPATCH*NSPLIT*4);
  int*   wsargi = (int*)  alloc((size_t)NPATCH*NSPLIT*4);
  float* ps     = (float*)alloc(NPATCH*4);
  int*   loc    = (int*)  alloc(NPATCH*4);
  float* bscore = (float*)alloc(NB*4);
  int*   brow   = (int*)  alloc(NB*4);
  int*   bnn    = (int*)  alloc(NB*4);
  float* dbank  = (float*)alloc((size_t)NB*MBANK*4);
  float* cv     = (float*)alloc(NB*CHUNKS*NNB*4);
  int*   ci     = (int*)  alloc(NB*CHUNKS*NNB*4);
  int*   supp   = (int*)  alloc(NB*NNB*4);
  float* dsup   = (float*)alloc(NB*NNB*4);
  float* gk     = (float*)alloc(KS*4);
  float* tmp    = (float*)alloc((size_t)NB*OUTW*OUTW*4);

  gk_kernel<<<1, 64, 0, stream>>>(gk);

  {
    int n = NB*C2*H2*W2;
    pool2_kernel<<<(n+255)/256, 256, 0, stream>>>(feat2, embb);
  }
  {
    int n = NB*C3*H3*W3;
    pool3_kernel<<<(n+255)/256, 256, 0, stream>>>(feat3, f3p);
  }
  {
    int n = NB*C3*H2*W2;
    up3_kernel<<<(n+255)/256, 256, 0, stream>>>(f3p, embb);
  }
  bank_prep_kernel<<<(MBANK*64)/256, 256, 0, stream>>>(bank, bankb, yn);
  norm_bf16_kernel<<<(NPATCH*64+255)/256, 256, 0, stream>>>(embb, xn, NPATCH);

  dist_min_mfma<<<NSPLIT*NT_N, 256, 0, stream>>>(embb, bankb, xn, yn, wsminv, wsargi);
  reduce_min_kernel<<<(NPATCH+255)/256, 256, 0, stream>>>(wsminv, wsargi, ps, loc);

  argmax_kernel<<<NB, 256, 0, stream>>>(ps, loc, bscore, brow, bnn);
  dbank_kernel<<<MBANK/4, 256, 0, stream>>>(bank, yn, bnn, dbank);
  top9_stage1<<<NB*CHUNKS, 256, 0, stream>>>(dbank, cv, ci);
  top9_stage2<<<NB, 128, 0, stream>>>(cv, ci, supp);
  dsup_kernel<<<(NB*NNB*64 + 255)/256, 256, 0, stream>>>(embb, bank, xn, yn, brow, supp, dsup);
  pred_kernel<<<1, 64, 0, stream>>>(dsup, bscore, out + NB*OUTW*OUTW);

  {
    upblurh_kernel<<<NB*OUTW, 256, 0, stream>>>(ps, gk, tmp);
    int n = NB*OUTW*OUTW;
    blurv_kernel<<<(n+255)/256, 256, 0, stream>>>(tmp, gk, out);
  }
}

// Round 4
// 702.756 us; speedup vs baseline: 9.6826x; 1.0349x over previous
//
#include <hip/hip_runtime.h>
#include <math.h>

#define NB 8
#define C2 512
#define C3 1024
#define H2 28
#define W2 28
#define H3 14
#define W3 14
#define EDIM 1536
#define PPB (H2*W2)            /* 784 */
#define NPATCH (NB*PPB)        /* 6272 */
#define MPAD 6400              /* 25*256 */
#define MBANK 20000
#define OUTW 224
#define NNB 9
#define KS 33
#define KR 16
#define NMT 25
#define NNT 79
#define NTSTRIDE 80
#define CHUNKS 8
#define CH (MBANK/CHUNKS)      /* 2500 */

typedef __attribute__((ext_vector_type(8))) short short8;
typedef __attribute__((ext_vector_type(4))) float f32x4;

#define LEXLT(va,ia,vb,ib) ((va) < (vb) || ((va)==(vb) && (ia)<(ib)))
#define CSWAP(va,ia,vb,ib) { if (LEXLT(va,ia,vb,ib)) { float _tv=(vb); int _ti=(ib); (vb)=(va); (ib)=(ia); (va)=_tv; (ia)=_ti; } }

#define BAR() asm volatile("s_barrier" ::: "memory")
#define WAITV4() asm volatile("s_waitcnt vmcnt(4)" ::: "memory")
#define WAITV0() asm volatile("s_waitcnt vmcnt(0)" ::: "memory")
#define WAITL0() asm volatile("s_waitcnt lgkmcnt(0)" ::: "memory")

__device__ __forceinline__ float bf2f(unsigned short u) {
  union { unsigned u; float f; } c; c.u = ((unsigned)u) << 16; return c.f;
}
__device__ __forceinline__ unsigned short f2bf(float f) {
  union { float f; unsigned u; } c; c.f = f;
  unsigned r = c.u + 0x7fff + ((c.u >> 16) & 1);
  return (unsigned short)(r >> 16);
}
__device__ __forceinline__ void gload16(const void* g, void* l) {
  __builtin_amdgcn_global_load_lds(
      (const __attribute__((address_space(1))) unsigned int*)g,
      (__attribute__((address_space(3))) unsigned int*)l, 16, 0, 0);
}

// ---------------- feature pooling / embedding (emb stored bf16) ----------------

__global__ void pool2_kernel(const float* __restrict__ in, unsigned short* __restrict__ emb) {
  int id = blockIdx.x*blockDim.x + threadIdx.x;
  if (id >= NB*C2*H2*W2) return;
  int w = id % W2, h = (id / W2) % H2, c = (id / (H2*W2)) % C2, b = id / (C2*H2*W2);
  const float* src = in + (size_t)(b*C2 + c)*H2*W2;
  float s = 0.f;
  #pragma unroll
  for (int dh=-1; dh<=1; ++dh) {
    int hh = h+dh; if (hh<0||hh>=H2) continue;
    #pragma unroll
    for (int dw=-1; dw<=1; ++dw) {
      int ww = w+dw; if (ww<0||ww>=W2) continue;
      s += src[hh*W2+ww];
    }
  }
  emb[((size_t)(b*PPB) + h*W2 + w)*EDIM + c] = f2bf(s * (1.f/9.f));
}

__global__ void pool3_kernel(const float* __restrict__ in, float* __restrict__ f3p) {
  int id = blockIdx.x*blockDim.x + threadIdx.x;
  if (id >= NB*C3*H3*W3) return;
  int w = id % W3, h = (id / W3) % H3, c = (id / (H3*W3)) % C3, b = id / (C3*H3*W3);
  const float* src = in + (size_t)(b*C3 + c)*H3*W3;
  float s = 0.f;
  #pragma unroll
  for (int dh=-1; dh<=1; ++dh) {
    int hh = h+dh; if (hh<0||hh>=H3) continue;
    #pragma unroll
    for (int dw=-1; dw<=1; ++dw) {
      int ww = w+dw; if (ww<0||ww>=W3) continue;
      s += src[hh*W3+ww];
    }
  }
  f3p[(size_t)id] = s * (1.f/9.f);
}

__global__ void up3_kernel(const float* __restrict__ f3p, unsigned short* __restrict__ emb) {
  int id = blockIdx.x*blockDim.x + threadIdx.x;
  if (id >= NB*C3*H2*W2) return;
  int j = id % W2, i = (id/W2)%H2, c = (id/(H2*W2))%C3, b = id/(C3*H2*W2);
  float sy = i*0.5f - 0.25f; sy = fminf(fmaxf(sy,0.f),(float)(H3-1));
  int y0 = (int)sy; int y1 = min(y0+1,H3-1); float fy = sy - (float)y0;
  float sx = j*0.5f - 0.25f; sx = fminf(fmaxf(sx,0.f),(float)(W3-1));
  int x0 = (int)sx; int x1 = min(x0+1,W3-1); float fx = sx - (float)x0;
  const float* p = f3p + (size_t)(b*C3+c)*H3*W3;
  float v = (1.f-fy)*((1.f-fx)*p[y0*W3+x0] + fx*p[y0*W3+x1])
          +      fy *((1.f-fx)*p[y1*W3+x0] + fx*p[y1*W3+x1]);
  emb[((size_t)(b*PPB) + i*W2 + j)*EDIM + C2 + c] = f2bf(v);
}

// ---------------- bank prep: fp32 -> bf16 + norms in one pass ----------------

__global__ void bank_prep_kernel(const float* __restrict__ bank, unsigned short* __restrict__ bankb,
                                 float* __restrict__ yn) {
  int w = (blockIdx.x*blockDim.x + threadIdx.x) >> 6;
  int lane = threadIdx.x & 63;
  if (w >= MBANK) return;
  const float4* p = reinterpret_cast<const float4*>(bank + (size_t)w*EDIM);
  ushort4* q = reinterpret_cast<ushort4*>(bankb + (size_t)w*EDIM);
  float acc = 0.f;
  #pragma unroll
  for (int k = 0; k < EDIM/4/64; ++k) {
    int k4 = lane + k*64;
    float4 v = p[k4];
    acc = fmaf(v.x,v.x,acc); acc = fmaf(v.y,v.y,acc);
    acc = fmaf(v.z,v.z,acc); acc = fmaf(v.w,v.w,acc);
    ushort4 o; o.x = f2bf(v.x); o.y = f2bf(v.y); o.z = f2bf(v.z); o.w = f2bf(v.w);
    q[k4] = o;
  }
  #pragma unroll
  for (int s = 32; s; s >>= 1) acc += __shfl_xor(acc, s);
  if (lane == 0) yn[w] = acc;
}

__global__ void norm_bf16_kernel(const unsigned short* __restrict__ src, float* __restrict__ norms, int rows) {
  int w = (blockIdx.x*blockDim.x + threadIdx.x) >> 6;
  int lane = threadIdx.x & 63;
  if (w >= rows) return;
  const ushort4* p = reinterpret_cast<const ushort4*>(src + (size_t)w*EDIM);
  float acc = 0.f;
  for (int k = lane; k < EDIM/4; k += 64) {
    ushort4 v = p[k];
    float a = bf2f(v.x), b = bf2f(v.y), c = bf2f(v.z), d = bf2f(v.w);
    acc = fmaf(a,a,acc); acc = fmaf(b,b,acc); acc = fmaf(c,c,acc); acc = fmaf(d,d,acc);
  }
  #pragma unroll
  for (int s = 32; s; s >>= 1) acc += __shfl_xor(acc, s);
  if (lane == 0) norms[w] = acc;
}

// ---------------- 256x256 8-phase MFMA distance GEMM + min/argmin ----------------
// 8 waves (2 Mx4 N), ring of 4 K32-slabs (A: 16KB, B: 16KB each) in 128 KiB LDS.
// Slab LDS layout: logical (row r in [0,256), kchunk ko in [0,4)) stored at
// byte (r>>1)*128 + ((((r&1)<<2)|ko) ^ ((r>>1)&7))*16  -- 128B-row XOR swizzle
// (round-3-verified: 0 bank conflicts). Staging: linear wave-uniform dest +
// pre-swizzled per-lane global source. Counted vmcnt(4) at phases 4/8 only.

__global__ __launch_bounds__(512, 2) void dist_min_mfma256(
    const unsigned short* __restrict__ A, const unsigned short* __restrict__ B,
    const float* __restrict__ xn, const float* __restrict__ yn,
    float* __restrict__ outv, int* __restrict__ outi)
{
  __shared__ __align__(16) unsigned char LDSC[131072];
  const int t = threadIdx.x;
  const int lane = t & 63, wid = t >> 6;
  const int wr = wid >> 2, wc = wid & 3;

  // bijective XCD swizzle (m204): consecutive wg within an XCD share the A-panel
  const int nwg = NMT*NNT;
  int orig = blockIdx.x;
  int xcd = orig & 7, loc = orig >> 3;
  int qq = nwg >> 3, rm = nwg & 7;
  int wg = (xcd < rm ? xcd*(qq+1) : rm*(qq+1) + (xcd-rm)*qq) + loc;
  const int mt = wg / NNT, nt = wg % NNT;
  const int m0 = mt*256, n0 = nt*256;

  // staging per-lane source offsets (inverse of the LDS swizzle)
  const int l3 = lane >> 3, l7 = lane & 7;
  const int D = l7 ^ l3;
  const int koS = (D & 3) << 4;
  const int rhi = D >> 2;
  const int r0 = wid*32 + (l3<<1) + rhi;
  const int r1 = r0 + 16;
  const char* Ac = (const char*)A + (size_t)m0*3072;
  const char* Bc = (const char*)B;
  const unsigned aoff0 = (unsigned)(r0*3072 + koS);
  const unsigned aoff1 = (unsigned)(r1*3072 + koS);
  int bn0 = n0 + r0; bn0 = bn0 < MBANK ? bn0 : MBANK-1;
  int bn1 = n0 + r1; bn1 = bn1 < MBANK ? bn1 : MBANK-1;
  const unsigned boff0 = (unsigned)bn0*3072u + (unsigned)koS;
  const unsigned boff1 = (unsigned)bn1*3072u + (unsigned)koS;
  char* const dstBase = (char*)LDSC + (wid << 11);

  // fragment read offsets (swizzled)
  const int h = lane & 15, g = lane >> 4;
  const int csw = (((h & 1) << 2) | g) ^ (h >> 1);
  const unsigned abyte = (unsigned)(((wr*128 + h) >> 1)*128 + csw*16);
  const unsigned bbyte = (unsigned)(((wc*64 + h) >> 1)*128 + csw*16);

  f32x4 acc[8][4];
  #pragma unroll
  for (int i = 0; i < 8; ++i)
    #pragma unroll
    for (int j = 0; j < 4; ++j) acc[i][j] = (f32x4){0.f,0.f,0.f,0.f};
  short8 bf[4];

  // prologue: stage slabs 0,1,2 (A then B each)
  #pragma unroll
  for (int s = 0; s < 3; ++s) {
    const unsigned sl = (unsigned)s*16384u;
    gload16(Ac + aoff0 + s*64, dstBase + sl);
    gload16(Ac + aoff1 + s*64, dstBase + sl + 1024);
    gload16(Bc + boff0 + s*64, dstBase + 65536u + sl);
    gload16(Bc + boff1 + s*64, dstBase + 65536u + sl + 1024);
  }
  WAITV4();
  BAR();

  for (int it = 0; it < 12; ++it) {
    const int sb = it << 2;
    #pragma unroll
    for (int ph = 0; ph < 8; ++ph) {
      const int cs = sb + (ph >> 1);
      const unsigned sA = (unsigned)(cs & 3)*16384u;
      short8 af[4];
      if ((ph & 1) == 0) {
        const unsigned sB = sA + 65536u;
        #pragma unroll
        for (int j = 0; j < 4; ++j)
          bf[j] = *(const short8*)(LDSC + sB + bbyte + j*1024);
        #pragma unroll
        for (int i = 0; i < 4; ++i)
          af[i] = *(const short8*)(LDSC + sA + abyte + i*1024);
      } else {
        #pragma unroll
        for (int i = 0; i < 4; ++i)
          af[i] = *(const short8*)(LDSC + sA + abyte + (i+4)*1024);
      }
      // stage one half-slab (A at even phases, B at odd) of slab ss
      int ss = sb + 3 + (ph >> 1); ss = ss < 48 ? ss : 47;
      {
        const unsigned dsl = (unsigned)(ss & 3)*16384u + ((ph & 1) ? 65536u : 0u);
        if (ph & 1) {
          gload16(Bc + boff0 + ss*64, dstBase + dsl);
          gload16(Bc + boff1 + ss*64, dstBase + dsl + 1024);
        } else {
          gload16(Ac + aoff0 + ss*64, dstBase + dsl);
          gload16(Ac + aoff1 + ss*64, dstBase + dsl + 1024);
        }
      }
      BAR();
      WAITL0();
      __builtin_amdgcn_s_setprio(1);
      const int fb = (ph & 1) << 2;
      #pragma unroll
      for (int i = 0; i < 4; ++i)
        #pragma unroll
        for (int j = 0; j < 4; ++j)
          acc[fb+i][j] = __builtin_amdgcn_mfma_f32_16x16x32_bf16(af[i], bf[j], acc[fb+i][j], 0, 0, 0);
      __builtin_amdgcn_s_setprio(0);
      if (ph == 3 || ph == 7) WAITV4();
      BAR();
    }
  }
  WAITV0();
  BAR();

  // epilogue: q = yn - 2*dot ; min+argmin over this block's 256 cols
  float ynv[4];
  #pragma unroll
  for (int j = 0; j < 4; ++j) {
    int col = n0 + wc*64 + j*16 + h;
    ynv[j] = col < MBANK ? yn[col] : INFINITY;
  }
  float* smin = (float*)LDSC;
  int* sidx = (int*)(LDSC + 4096);
  #pragma unroll
  for (int i = 0; i < 8; ++i) {
    #pragma unroll
    for (int r = 0; r < 4; ++r) {
      float v = INFINITY; int ix = 0x7fffffff;
      #pragma unroll
      for (int j = 0; j < 4; ++j) {
        float q = fmaf(-2.f, acc[i][j][r], ynv[j]);
        int col = n0 + wc*64 + j*16 + h;
        if (q < v || (q == v && col < ix)) { v = q; ix = col; }
      }
      #pragma unroll
      for (int m = 1; m < 16; m <<= 1) {
        float ov = __shfl_xor(v, m);
        int   oi = __shfl_xor(ix, m);
        if (ov < v || (ov == v && oi < ix)) { v = ov; ix = oi; }
      }
      if (h == 0) {
        int rl = wr*128 + i*16 + g*4 + r;
        smin[rl*4 + wc] = v;
        sidx[rl*4 + wc] = ix;
      }
    }
  }
  __syncthreads();
  if (t < 256) {
    float v = smin[t*4]; int ix = sidx[t*4];
    #pragma unroll
    for (int w = 1; w < 4; ++w) {
      float ov = smin[t*4+w]; int oi = sidx[t*4+w];
      if (ov < v || (ov == v && oi < ix)) { v = ov; ix = oi; }
    }
    int row = m0 + t;
    if (row < NPATCH) {
      float d = sqrtf(fmaxf(xn[row] + v, 0.f));
      outv[(size_t)row*NTSTRIDE + nt] = d;
      outi[(size_t)row*NTSTRIDE + nt] = ix;
    }
  }
}

__global__ void reduce_min_kernel(const float* __restrict__ outv, const int* __restrict__ outi,
                                  float* __restrict__ ps, int* __restrict__ loc) {
  int r = blockIdx.x*blockDim.x + threadIdx.x;
  if (r >= NPATCH) return;
  float bv = INFINITY; int bi = 0x7fffffff;
  for (int s = 0; s < NNT; ++s) {
    float v = outv[(size_t)r*NTSTRIDE + s];
    int  ix = outi[(size_t)r*NTSTRIDE + s];
    if (v < bv || (v == bv && ix < bi)) { bv = v; bi = ix; }
  }
  ps[r] = bv; loc[r] = bi;
}

// ---------------- anomaly score ----------------

__global__ void argmax_kernel(const float* __restrict__ ps, const int* __restrict__ loc,
                              float* __restrict__ bscore, int* __restrict__ brow, int* __restrict__ bnn) {
  __shared__ float sv[256]; __shared__ int si[256];
  int b = blockIdx.x, t = threadIdx.x;
  float bv = -INFINITY; int bi = 0x7fffffff;
  for (int p = t; p < PPB; p += 256) {
    float v = ps[b*PPB + p];
    if (v > bv || (v == bv && p < bi)) { bv = v; bi = p; }
  }
  sv[t] = bv; si[t] = bi; __syncthreads();
  for (int s = 128; s; s >>= 1) {
    if (t < s) {
      if (sv[t+s] > sv[t] || (sv[t+s] == sv[t] && si[t+s] < si[t])) { sv[t] = sv[t+s]; si[t] = si[t+s]; }
    }
    __syncthreads();
  }
  if (t == 0) {
    bscore[b] = sv[0];
    brow[b]   = b*PPB + si[0];
    bnn[b]    = loc[b*PPB + si[0]];
  }
}

// one pass over the fp32 bank, all 8 batches per row
__global__ __launch_bounds__(256) void dbank_kernel(
    const float* __restrict__ bank, const float* __restrict__ yn,
    const int* __restrict__ bnn, float* __restrict__ dbank)
{
  __shared__ float xs[8][EDIM];
  int t = threadIdx.x;
  for (int idx = t*4; idx < 8*EDIM; idx += 256*4) {
    int b = idx / EDIM, k = idx % EDIM;
    float4 v = *reinterpret_cast<const float4*>(bank + (size_t)bnn[b]*EDIM + k);
    *reinterpret_cast<float4*>(&xs[b][k]) = v;
  }
  __syncthreads();
  int m = blockIdx.x*4 + (t >> 6);
  if (m >= MBANK) return;
  int lane = t & 63;
  const float4* yp = reinterpret_cast<const float4*>(bank + (size_t)m*EDIM);
  float acc[8] = {0.f,0.f,0.f,0.f,0.f,0.f,0.f,0.f};
  for (int k4 = lane; k4 < EDIM/4; k4 += 64) {
    float4 y = yp[k4];
    int k = k4*4;
    #pragma unroll
    for (int b = 0; b < 8; ++b) {
      acc[b] = fmaf(y.x, xs[b][k+0], acc[b]);
      acc[b] = fmaf(y.y, xs[b][k+1], acc[b]);
      acc[b] = fmaf(y.z, xs[b][k+2], acc[b]);
      acc[b] = fmaf(y.w, xs[b][k+3], acc[b]);
    }
  }
  #pragma unroll
  for (int b = 0; b < 8; ++b) {
    float a = acc[b];
    #pragma unroll
    for (int s = 32; s; s >>= 1) a += __shfl_xor(a, s);
    acc[b] = a;
  }
  if (lane == 0) {
    #pragma unroll
    for (int b = 0; b < 8; ++b) {
      int nn = bnn[b];
      float d2 = yn[nn] - 2.f*acc[b] + yn[m];
      dbank[(size_t)b*MBANK + m] = sqrtf(fmaxf(d2, 0.f));
    }
  }
}

// ---------------- parallel top-9: stage 1 (per-chunk) ----------------

__global__ __launch_bounds__(256) void top9_stage1(const float* __restrict__ dbank,
                                                   float* __restrict__ cv, int* __restrict__ ci) {
  int b = blockIdx.x / CHUNKS, ch = blockIdx.x % CHUNKS;
  const float* db = dbank + (size_t)b*MBANK + ch*CH;
  int t = threadIdx.x;

  float v0=INFINITY,v1=INFINITY,v2=INFINITY,v3=INFINITY,v4=INFINITY,
        v5=INFINITY,v6=INFINITY,v7=INFINITY,v8=INFINITY;
  int i0=0x7fffffff,i1=0x7fffffff,i2=0x7fffffff,i3=0x7fffffff,i4=0x7fffffff,
      i5=0x7fffffff,i6=0x7fffffff,i7=0x7fffffff,i8=0x7fffffff;

  for (int s = 0; s < (CH+255)/256; ++s) {
    int m = t + s*256;
    if (m < CH) {
      float nv = db[m]; int ni = ch*CH + m;
      if (LEXLT(nv,ni,v8,i8)) {
        v8 = nv; i8 = ni;
        CSWAP(v8,i8,v7,i7); CSWAP(v7,i7,v6,i6); CSWAP(v6,i6,v5,i5); CSWAP(v5,i5,v4,i4);
        CSWAP(v4,i4,v3,i3); CSWAP(v3,i3,v2,i2); CSWAP(v2,i2,v1,i1); CSWAP(v1,i1,v0,i0);
      }
    }
  }

  __shared__ float sv[256*9];
  __shared__ int   si[256*9];
  __shared__ float rv[256]; __shared__ int ri[256]; __shared__ int rp[256];
  sv[t*9+0]=v0; sv[t*9+1]=v1; sv[t*9+2]=v2; sv[t*9+3]=v3; sv[t*9+4]=v4;
  sv[t*9+5]=v5; sv[t*9+6]=v6; sv[t*9+7]=v7; sv[t*9+8]=v8;
  si[t*9+0]=i0; si[t*9+1]=i1; si[t*9+2]=i2; si[t*9+3]=i3; si[t*9+4]=i4;
  si[t*9+5]=i5; si[t*9+6]=i6; si[t*9+7]=i7; si[t*9+8]=i8;
  __syncthreads();

  for (int r = 0; r < NNB; ++r) {
    float bv = INFINITY; int bix = 0x7fffffff; int bp = -1;
    #pragma unroll
    for (int u = 0; u < 9; ++u) {
      float v = sv[t*9+u]; int ix = si[t*9+u];
      if (LEXLT(v,ix,bv,bix)) { bv = v; bix = ix; bp = t*9+u; }
    }
    rv[t] = bv; ri[t] = bix; rp[t] = bp; __syncthreads();
    for (int s = 128; s; s >>= 1) {
      if (t < s) {
        if (LEXLT(rv[t+s],ri[t+s],rv[t],ri[t])) { rv[t]=rv[t+s]; ri[t]=ri[t+s]; rp[t]=rp[t+s]; }
      }
      __syncthreads();
    }
    if (t == 0) {
      cv[blockIdx.x*NNB + r] = rv[0];
      ci[blockIdx.x*NNB + r] = ri[0];
      sv[rp[0]] = INFINITY; si[rp[0]] = 0x7fffffff;
    }
    __syncthreads();
  }
}

// ---------------- top-9: stage 2 (merge 8 chunks x 9) ----------------

__global__ void top9_stage2(const float* __restrict__ cv, const int* __restrict__ ci,
                            int* __restrict__ support) {
  __shared__ float sv[128]; __shared__ int si[128];
  __shared__ float wv[128]; __shared__ int wi[128]; __shared__ int wp[128];
  int b = blockIdx.x, t = threadIdx.x;
  if (t < CHUNKS*NNB) { sv[t] = cv[b*CHUNKS*NNB + t]; si[t] = ci[b*CHUNKS*NNB + t]; }
  else { sv[t] = INFINITY; si[t] = 0x7fffffff; }
  __syncthreads();
  for (int r = 0; r < NNB; ++r) {
    wv[t] = sv[t]; wi[t] = si[t]; wp[t] = t; __syncthreads();
    for (int s = 64; s; s >>= 1) {
      if (t < s) {
        if (LEXLT(wv[t+s],wi[t+s],wv[t],wi[t])) { wv[t]=wv[t+s]; wi[t]=wi[t+s]; wp[t]=wp[t+s]; }
      }
      __syncthreads();
    }
    if (t == 0) {
      support[b*NNB + r] = wi[0];
      sv[wp[0]] = INFINITY; si[wp[0]] = 0x7fffffff;
    }
    __syncthreads();
  }
}

__global__ void dsup_kernel(const unsigned short* __restrict__ embb, const float* __restrict__ bank,
                            const float* __restrict__ xn, const float* __restrict__ yn,
                            const int* __restrict__ brow, const int* __restrict__ support,
                            float* __restrict__ dsup) {
  int w = (blockIdx.x*blockDim.x + threadIdx.x) >> 6;
  int lane = threadIdx.x & 63;
  if (w >= NB*NNB) return;
  int b = w / NNB, j = w % NNB;
  int row = brow[b]; int sup = support[b*NNB + j];
  const unsigned short* x = embb + (size_t)row*EDIM;
  const float* y = bank + (size_t)sup*EDIM;
  float acc = 0.f;
  for (int k = lane; k < EDIM; k += 64) acc = fmaf(bf2f(x[k]), y[k], acc);
  #pragma unroll
  for (int s = 32; s; s >>= 1) acc += __shfl_xor(acc, s);
  if (lane == 0) dsup[b*NNB + j] = sqrtf(fmaxf(xn[row] - 2.f*acc + yn[sup], 0.f));
}

__global__ void pred_kernel(const float* __restrict__ dsup, const float* __restrict__ bscore,
                            float* __restrict__ out) {
  int b = threadIdx.x;
  if (b >= NB) return;
  float d[NNB]; float mx = -INFINITY;
  #pragma unroll
  for (int j = 0; j < NNB; ++j) { d[j] = dsup[b*NNB + j]; mx = fmaxf(mx, d[j]); }
  float s = 0.f;
  #pragma unroll
  for (int j = 0; j < NNB; ++j) s += expf(d[j] - mx);
  float w = 1.f - expf(d[0] - mx) / s;
  out[b] = w * bscore[b];
}

// ---------------- anomaly map ----------------

__global__ void gk_kernel(float* __restrict__ gk) {
  if (threadIdx.x == 0 && blockIdx.x == 0) {
    float w[KS]; float s = 0.f;
    for (int t = 0; t < KS; ++t) {
      float x = (float)t - (float)KR;
      w[t] = expf(-(x*x) / (2.f*4.f*4.f));
      s += w[t];
    }
    for (int t = 0; t < KS; ++t) gk[t] = w[t] / s;
  }
}

__device__ __forceinline__ int refl224(int x) {
  if (x < 0) return -x;
  if (x > OUTW-1) return 2*(OUTW-1) - x;
  return x;
}

__global__ __launch_bounds__(256) void upblurh_kernel(const float* __restrict__ ps,
                                                      const float* __restrict__ gk,
                                                      float* __restrict__ tmp) {
  int b = blockIdx.x / OUTW, i = blockIdx.x % OUTW;
  int t = threadIdx.x;
  __shared__ float l[W2];
  __shared__ float gks[KS];
  if (t < KS) gks[t] = gk[t];
  float sy = ((float)i + 0.5f)*0.125f - 0.5f; sy = fminf(fmaxf(sy,0.f),(float)(H2-1));
  int y0 = (int)sy; int y1 = min(y0+1,H2-1); float fy = sy - (float)y0;
  if (t < W2) {
    const float* p = ps + b*PPB;
    l[t] = (1.f-fy)*p[y0*W2+t] + fy*p[y1*W2+t];
  }
  __syncthreads();
  if (t >= OUTW) return;
  float s = 0.f;
  #pragma unroll
  for (int v = 0; v < KS; ++v) {
    int jj = refl224(t - KR + v);
    float sx = ((float)jj + 0.5f)*0.125f - 0.5f; sx = fminf(fmaxf(sx,0.f),(float)(W2-1));
    int x0 = (int)sx; int x1 = min(x0+1,W2-1); float fx = sx - (float)x0;
    s = fmaf(gks[v], (1.f-fx)*l[x0] + fx*l[x1], s);
  }
  tmp[((size_t)b*OUTW + i)*OUTW + t] = s;
}

__global__ void blurv_kernel(const float* __restrict__ in, const float* __restrict__ gk,
                             float* __restrict__ out) {
  int id = blockIdx.x*blockDim.x + threadIdx.x;
  if (id >= NB*OUTW*OUTW) return;
  int j = id % OUTW, i = (id/OUTW) % OUTW, b = id/(OUTW*OUTW);
  float s = 0.f;
  #pragma unroll
  for (int u = 0; u < KS; ++u) {
    int ii = refl224(i - KR + u);
    s = fmaf(gk[u], in[((size_t)b*OUTW + ii)*OUTW + j], s);
  }
  out[id] = s;
}

// ---------------- launch ----------------

extern "C" void kernel_launch(void* const* d_in, const int* in_sizes, int n_in,
                              void* d_out, int out_size, void* d_ws, size_t ws_size,
                              hipStream_t stream) {
  const float* feat2 = (const float*)d_in[0];
  const float* feat3 = (const float*)d_in[1];
  const float* bank  = (const float*)d_in[2];
  float* out = (float*)d_out;

  char* base = (char*)d_ws;
  size_t off = 0;
  auto alloc = [&](size_t nbytes) -> char* {
    char* p = base + off;
    off += ((nbytes + 255) & ~(size_t)255);
    return p;
  };
  unsigned short* embb  = (unsigned short*)alloc((size_t)MPAD*EDIM*2);
  unsigned short* bankb = (unsigned short*)alloc((size_t)MBANK*EDIM*2);
  float* f3p    = (float*)alloc((size_t)NB*C3*H3*W3*4);
  float* yn     = (float*)alloc(MBANK*4);
  float* xn     = (float*)alloc(NPATCH*4);
  float* wsminv = (float*)alloc((size_t)NPATCH*NTSTRIDE*4);
  int*   wsargi = (int*)  alloc((size_t)NPATCH*NTSTRIDE*4);
  float* ps     = (float*)alloc(NPATCH*4);
  int*   loc    = (int*)  alloc(NPATCH*4);
  float* bscore = (float*)alloc(NB*4);
  int*   brow   = (int*)  alloc(NB*4);
  int*   bnn    = (int*)  alloc(NB*4);
  float* dbank  = (float*)alloc((size_t)NB*MBANK*4);
  float* cv     = (float*)alloc(NB*CHUNKS*NNB*4);
  int*   ci     = (int*)  alloc(NB*CHUNKS*NNB*4);
  int*   supp   = (int*)  alloc(NB*NNB*4);
  float* dsup   = (float*)alloc(NB*NNB*4);
  float* gk     = (float*)alloc(KS*4);
  float* tmp    = (float*)alloc((size_t)NB*OUTW*OUTW*4);

  gk_kernel<<<1, 64, 0, stream>>>(gk);

  {
    int n = NB*C2*H2*W2;
    pool2_kernel<<<(n+255)/256, 256, 0, stream>>>(feat2, embb);
  }
  {
    int n = NB*C3*H3*W3;
    pool3_kernel<<<(n+255)/256, 256, 0, stream>>>(feat3, f3p);
  }
  {
    int n = NB*C3*H2*W2;
    up3_kernel<<<(n+255)/256, 256, 0, stream>>>(f3p, embb);
  }
  bank_prep_kernel<<<(MBANK*64)/256, 256, 0, stream>>>(bank, bankb, yn);
  norm_bf16_kernel<<<(NPATCH*64+255)/256, 256, 0, stream>>>(embb, xn, NPATCH);

  dist_min_mfma256<<<NMT*NNT, 512, 0, stream>>>(embb, bankb, xn, yn, wsminv, wsargi);
  reduce_min_kernel<<<(NPATCH+255)/256, 256, 0, stream>>>(wsminv, wsargi, ps, loc);

  argmax_kernel<<<NB, 256, 0, stream>>>(ps, loc, bscore, brow, bnn);
  dbank_kernel<<<MBANK/4, 256, 0, stream>>>(bank, yn, bnn, dbank);
  top9_stage1<<<NB*CHUNKS, 256, 0, stream>>>(dbank, cv, ci);
  top9_stage2<<<NB, 128, 0, stream>>>(cv, ci, supp);
  dsup_kernel<<<(NB*NNB*64 + 255)/256, 256, 0, stream>>>(embb, bank, xn, yn, brow, supp, dsup);
  pred_kernel<<<1, 64, 0, stream>>>(dsup, bscore, out + NB*OUTW*OUTW);

  {
    upblurh_kernel<<<NB*OUTW, 256, 0, stream>>>(ps, gk, tmp);
    int n = NB*OUTW*OUTW;
    blurv_kernel<<<(n+255)/256, 256, 0, stream>>>(tmp, gk, out);
  }
}